// Round 9
// baseline (181.651 us; speedup 1.0000x reference)
//
#include <hip/hip_runtime.h>
#include <math.h>

// ---------------------------------------------------------------------------
// bf16-MFMA implementation, both layers merged (z=2), global_load_lds staging.
//  - all dense GEMMs: 2-term split (A hi/lo × B hi) — R7/R8-proven numerics
//  - attention + sim: plain bf16 MFMA
//  - R9: counted-vmcnt pipeline (T4) in gemm_split/sim_mfma: raw s_barrier,
//    s_waitcnt vmcnt(N) — prefetch stays in flight across barriers.
// ---------------------------------------------------------------------------

typedef float f32x4 __attribute__((ext_vector_type(4)));
typedef short s16x8 __attribute__((ext_vector_type(8)));
typedef unsigned short u16;
typedef unsigned int u32;

#define NTOK 1024
#define PL 512
#define QSCALE 0.04419417382415922f  // 1/sqrt(512)

#define WAITV(n) asm volatile("s_waitcnt vmcnt(" #n ")" ::: "memory")
#define WAITLGKM asm volatile("s_waitcnt lgkmcnt(0)" ::: "memory")

__device__ inline u16 f2bf(float f) {
    unsigned u = __builtin_bit_cast(unsigned, f);
    unsigned r = u + 0x7fffu + ((u >> 16) & 1u);   // RNE
    return (u16)(r >> 16);
}
__device__ inline float bf2f(u16 h) {
    unsigned u = ((unsigned)h) << 16;
    return __builtin_bit_cast(float, u);
}

__device__ inline void gll16(const void* g, void* l) {
    __builtin_amdgcn_global_load_lds(
        (const __attribute__((address_space(1))) u32*)g,
        (__attribute__((address_space(3))) u32*)l, 16, 0, 0);
}

// ---------------------------------------------------------------------------
// x -> hi/lo bf16 split (elementwise)
// ---------------------------------------------------------------------------
__global__ __launch_bounds__(256) void convert_x(const float* __restrict__ X,
    u16* __restrict__ hi, u16* __restrict__ lo)
{
    const int i = (blockIdx.x * 256 + threadIdx.x) * 4;
    float4 v = *(const float4*)&X[i];
    float vv[4] = {v.x, v.y, v.z, v.w};
    #pragma unroll
    for (int j = 0; j < 4; j++) {
        u16 h = f2bf(vv[j]);
        hi[i + j] = h;
        lo[i + j] = f2bf(vv[j] - bf2f(h));
    }
}

// ---------------------------------------------------------------------------
// W [512][N] f32 -> Wt [N][512] bf16 hi (tiled transpose), z = layer
// ---------------------------------------------------------------------------
__global__ __launch_bounds__(256) void convert_wt(const float* __restrict__ W0,
    const float* __restrict__ W1, u16* __restrict__ WhiB, const size_t dLS, const int N)
{
    const float* W = blockIdx.z ? W1 : W0;
    u16* Whi = WhiB + (size_t)blockIdx.z * dLS;
    __shared__ float T[32][36];
    const int k0 = blockIdx.x * 32, n0 = blockIdx.y * 32;
    const int tr = threadIdx.x >> 3, tc = (threadIdx.x & 7) * 4;
    *(float4*)&T[tr][tc] = *(const float4*)&W[(size_t)(k0 + tr) * N + n0 + tc];
    __syncthreads();
    const size_t o = (size_t)(n0 + tr) * 512 + k0 + tc;
    #pragma unroll
    for (int j = 0; j < 4; j++) Whi[o + j] = f2bf(T[tc + j][tr]);
}

// ---------------------------------------------------------------------------
// 2-term split-bf16 MFMA GEMM, z = layer. A[4096][512] (hi/lo) x Bt[N][512] (hi).
// EPI: 0 = qkv scatter (Q scaled, K, Vt), 1 = gelu -> hi/lo, 2 = plain hi/lo.
// BK=32; counted-vmcnt 2-deep pipeline: per-wave loads/stage = 6 (BM=128) or 4.
// ---------------------------------------------------------------------------
template<int BM, int EPI>
__global__ __launch_bounds__(256) void gemm_split(
    const u16* __restrict__ AhiB, const u16* __restrict__ AloB, const size_t aLS,
    const u16* __restrict__ BhiB, const size_t bLS,
    const float* __restrict__ bias0, const float* __restrict__ bias1, const int Ncols,
    u16* __restrict__ qq, u16* __restrict__ kkp, u16* __restrict__ vvp,
    u16* __restrict__ oh0, u16* __restrict__ oh1,
    u16* __restrict__ ol0, u16* __restrict__ ol1)
{
    constexpr int FM = BM / 32;
    __shared__ u16 Ah[2][BM * 32], Al[2][BM * 32], Bh[2][128 * 32];
    const int z = blockIdx.z;
    const u16* Ahi = AhiB + (size_t)z * aLS;
    const u16* Alo = AloB + (size_t)z * aLS;
    const u16* Bhi = BhiB + (size_t)z * bLS;
    const float* bias = z ? bias1 : bias0;
    u16* oh = z ? oh1 : oh0;
    u16* ol = z ? ol1 : ol0;

    const int t = threadIdx.x, l = t & 63, w = t >> 6;
    const int lr = l & 15, lg = l >> 4;
    const int wm = w >> 1, wn = w & 1;
    const int m0 = blockIdx.x * BM, n0 = blockIdx.y * 128;
    const int srow = l >> 2, sch = l & 3;    // staging lane coords (16 rows/KB)

    f32x4 acc[FM][4];
    #pragma unroll
    for (int i = 0; i < FM; i++)
        #pragma unroll
        for (int j = 0; j < 4; j++) acc[i][j] = f32x4{0.f, 0.f, 0.f, 0.f};

    auto stage = [&](int bufi, int k0) {
        #pragma unroll
        for (int i = 0; i < BM / 64; i++) {
            const int j = w * (BM / 64) + i;
            const int r = j * 16 + srow;
            const int ck = sch ^ ((r >> 1) & 3);
            const size_t g = (size_t)(m0 + r) * 512 + k0 + ck * 8;
            gll16(&Ahi[g], &Ah[bufi][j * 512]);
            gll16(&Alo[g], &Al[bufi][j * 512]);
        }
        #pragma unroll
        for (int i = 0; i < 2; i++) {
            const int j = w * 2 + i;
            const int r = j * 16 + srow;
            const int ck = sch ^ ((r >> 1) & 3);
            gll16(&Bhi[(size_t)(n0 + r) * 512 + k0 + ck * 8], &Bh[bufi][j * 512]);
        }
    };

    stage(0, 0);
    stage(1, 32);
    for (int kt = 0; kt < 16; kt++) {
        const int buf = kt & 1;
        // wait for THIS tile's loads only; next tile's stay in flight
        if (kt < 15) { if constexpr (BM == 128) WAITV(6); else WAITV(4); }
        else WAITV(0);
        __builtin_amdgcn_s_barrier();

        s16x8 ah[FM], al[FM];
        #pragma unroll
        for (int fm = 0; fm < FM; fm++) {
            const int r = wm * (BM / 2) + fm * 16 + lr;
            const int d = r * 32 + ((lg ^ ((r >> 1) & 3)) << 3);
            ah[fm] = *(const s16x8*)&Ah[buf][d];
            al[fm] = *(const s16x8*)&Al[buf][d];
        }
        #pragma unroll
        for (int fn = 0; fn < 4; fn++) {
            const int r = wn * 64 + fn * 16 + lr;
            const int d = r * 32 + ((lg ^ ((r >> 1) & 3)) << 3);
            s16x8 bh = *(const s16x8*)&Bh[buf][d];
            #pragma unroll
            for (int fm = 0; fm < FM; fm++) {
                acc[fm][fn] = __builtin_amdgcn_mfma_f32_16x16x32_bf16(ah[fm], bh, acc[fm][fn], 0, 0, 0);
                acc[fm][fn] = __builtin_amdgcn_mfma_f32_16x16x32_bf16(al[fm], bh, acc[fm][fn], 0, 0, 0);
            }
        }
        WAITLGKM;                              // my reads of buf retired
        __builtin_amdgcn_sched_barrier(0);
        __builtin_amdgcn_s_barrier();          // all waves done reading buf
        if (kt < 14) stage(buf, (kt + 2) * 32);
    }
    // epilogue
    #pragma unroll
    for (int fm = 0; fm < FM; fm++)
        #pragma unroll
        for (int fn = 0; fn < 4; fn++)
            #pragma unroll
            for (int rg = 0; rg < 4; rg++) {
                const int r = m0 + wm * (BM / 2) + fm * 16 + lg * 4 + rg;
                const int c = n0 + wn * 64 + fn * 16 + lr;
                float v = acc[fm][fn][rg] + bias[c];
                if constexpr (EPI == 0) {
                    const int part = c >> 9, c2 = c & 511;
                    const int h = c2 & 7, dd = c2 >> 3;
                    const int b = r >> 10, n = r & 1023;
                    const size_t bh_ = (size_t)(b * 8 + h);
                    const size_t zo = (size_t)z * 2097152;
                    if (part == 0)      qq [zo + (bh_ * 1024 + n) * 64 + dd] = f2bf(v * QSCALE);
                    else if (part == 1) kkp[zo + (bh_ * 1024 + n) * 64 + dd] = f2bf(v);
                    else                vvp[zo + (bh_ * 64 + dd) * 1024 + n] = f2bf(v);
                } else {
                    float gl = v;
                    if constexpr (EPI == 1)
                        gl = 0.5f * v * (1.f + erff(v * 0.70710678118654752f));
                    u16 hv = f2bf(gl);
                    oh[(size_t)r * Ncols + c] = hv;
                    ol[(size_t)r * Ncols + c] = f2bf(gl - bf2f(hv));
                }
            }
}

// ---------------------------------------------------------------------------
// Flash attention, bf16 MFMA, z = layer (z==0 causal, z==1 anti-causal).
// K/Vt tiles staged in LDS via global_load_lds, double-buffered. (unchanged)
// ---------------------------------------------------------------------------
__global__ __launch_bounds__(256) void attn_mfma(const u16* __restrict__ Qg,
    const u16* __restrict__ Kg, const u16* __restrict__ Vtg,
    float* __restrict__ AO0, float* __restrict__ AO1)
{
    __shared__ u16 Ks[2][64 * 64];
    __shared__ u16 Vs[2][64 * 64];
    __shared__ u16 Ps[4][16 * 72];
    const int t = threadIdx.x, l = t & 63, w = t >> 6;
    const int lr = l & 15, lg = l >> 4;
    const int z = blockIdx.z;
    const int causal = (z == 0);
    const int bh = blockIdx.x;
    const int b = bh >> 3, h = bh & 7;
    const int qt = causal ? (15 - (int)blockIdx.y) : (int)blockIdx.y;  // long jobs first
    const u16* Qb = Qg + (size_t)(z * 32 + bh) * (NTOK * 64);
    const u16* Kb = Kg + (size_t)(z * 32 + bh) * (NTOK * 64);
    const u16* Vb = Vtg + (size_t)(z * 32 + bh) * (64 * NTOK);
    float* AO = z ? AO1 : AO0;
    const int q0 = qt * 64 + w * 16;

    s16x8 aq[2];
    aq[0] = *(const s16x8*)&Qb[(size_t)(q0 + lr) * 64 + lg * 8];
    aq[1] = *(const s16x8*)&Qb[(size_t)(q0 + lr) * 64 + 32 + lg * 8];

    f32x4 o[4];
    float m_[4], l_[4];
    #pragma unroll
    for (int f = 0; f < 4; f++) o[f] = f32x4{0.f, 0.f, 0.f, 0.f};
    #pragma unroll
    for (int r = 0; r < 4; r++) { m_[r] = -INFINITY; l_[r] = 0.f; }

    const int kt0 = causal ? 0 : qt, kt1 = causal ? qt : 15;

    auto stage = [&](int bufi, int kt) {
        #pragma unroll
        for (int i = 0; i < 2; i++) {
            const int j = w * 2 + i;
            const int r = j * 8 + (l >> 3);
            const int ck = (l & 7) ^ (r & 7);
            gll16(Kb + (size_t)(kt * 64 + r) * 64 + ck * 8, &Ks[bufi][j * 512]);
        }
        #pragma unroll
        for (int i = 0; i < 2; i++) {
            const int j = w * 2 + i;
            const int dim = j * 8 + (l >> 3);
            const int ck = (l & 7) ^ (dim & 7);
            gll16(Vb + (size_t)dim * NTOK + kt * 64 + ck * 8, &Vs[bufi][j * 512]);
        }
    };

    stage(0, kt0);
    __syncthreads();
    int buf = 0;
    for (int kt = kt0; kt <= kt1; kt++) {
        if (kt < kt1) stage(buf ^ 1, kt + 1);
        f32x4 s[4];
        #pragma unroll
        for (int f = 0; f < 4; f++) s[f] = f32x4{0.f, 0.f, 0.f, 0.f};
        #pragma unroll
        for (int kk = 0; kk < 2; kk++)
            #pragma unroll
            for (int f = 0; f < 4; f++) {
                const int row = f * 16 + lr;
                const int ch = kk * 4 + lg;
                s16x8 bk = *(const s16x8*)&Ks[buf][row * 64 + ((ch ^ (row & 7)) << 3)];
                s[f] = __builtin_amdgcn_mfma_f32_16x16x32_bf16(aq[kk], bk, s[f], 0, 0, 0);
            }
        if (kt == qt) {
            #pragma unroll
            for (int f = 0; f < 4; f++) {
                const int key = kt * 64 + f * 16 + lr;
                #pragma unroll
                for (int r = 0; r < 4; r++) {
                    const int q = q0 + lg * 4 + r;
                    if (causal ? (key > q) : (key < q)) s[f][r] = -INFINITY;
                }
            }
        }
        float scale[4];
        #pragma unroll
        for (int r = 0; r < 4; r++) {
            float rm = fmaxf(fmaxf(s[0][r], s[1][r]), fmaxf(s[2][r], s[3][r]));
            #pragma unroll
            for (int off = 1; off < 16; off <<= 1) rm = fmaxf(rm, __shfl_xor(rm, off));
            const float mn = fmaxf(m_[r], rm);
            scale[r] = __expf(m_[r] - mn);
            float ps = 0.f;
            #pragma unroll
            for (int f = 0; f < 4; f++) { float p = __expf(s[f][r] - mn); s[f][r] = p; ps += p; }
            #pragma unroll
            for (int off = 1; off < 16; off <<= 1) ps += __shfl_xor(ps, off);
            l_[r] = l_[r] * scale[r] + ps;
            m_[r] = mn;
        }
        #pragma unroll
        for (int f = 0; f < 4; f++)
            #pragma unroll
            for (int r = 0; r < 4; r++)
                Ps[w][(lg * 4 + r) * 72 + f * 16 + lr] = f2bf(s[f][r]);
        #pragma unroll
        for (int f = 0; f < 4; f++)
            #pragma unroll
            for (int r = 0; r < 4; r++) o[f][r] *= scale[r];
        #pragma unroll
        for (int kk = 0; kk < 2; kk++) {
            s16x8 ap = *(const s16x8*)&Ps[w][lr * 72 + kk * 32 + lg * 8];
            #pragma unroll
            for (int f = 0; f < 4; f++) {
                const int row = f * 16 + lr;
                const int ch = kk * 4 + lg;
                s16x8 bv = *(const s16x8*)&Vs[buf][row * 64 + ((ch ^ (row & 7)) << 3)];
                o[f] = __builtin_amdgcn_mfma_f32_16x16x32_bf16(ap, bv, o[f], 0, 0, 0);
            }
        }
        __syncthreads();
        buf ^= 1;
    }
    #pragma unroll
    for (int f = 0; f < 4; f++)
        #pragma unroll
        for (int r = 0; r < 4; r++)
            AO[(size_t)(b * NTOK + q0 + lg * 4 + r) * PL + h * 64 + f * 16 + lr] = o[f][r] / l_[r];
}

// ---------------------------------------------------------------------------
// add+LN A: x(f32)+attn(f32) -> LN -> hi/lo bf16. z = layer.
// ---------------------------------------------------------------------------
__global__ __launch_bounds__(256) void add_ln_a(const float* __restrict__ X,
    const float* __restrict__ A0, const float* __restrict__ A1,
    const float* __restrict__ g0, const float* __restrict__ g1,
    const float* __restrict__ be0, const float* __restrict__ be1,
    u16* __restrict__ OhiB, u16* __restrict__ OloB, const size_t oLS)
{
    const int z = blockIdx.z;
    const float* A = z ? A1 : A0;
    const float* g = z ? g1 : g0;
    const float* be = z ? be1 : be0;
    u16* Ohi = OhiB + (size_t)z * oLS;
    u16* Olo = OloB + (size_t)z * oLS;
    const int row = blockIdx.x * 4 + (threadIdx.x >> 6);
    const int lane = threadIdx.x & 63;
    const float* xr = X + (size_t)row * PL;
    const float* ar = A + (size_t)row * PL;
    float v[8];
    float sum = 0.f;
    #pragma unroll
    for (int u = 0; u < 8; u++) { v[u] = xr[lane + u * 64] + ar[lane + u * 64]; sum += v[u]; }
    #pragma unroll
    for (int o = 32; o > 0; o >>= 1) sum += __shfl_xor(sum, o);
    const float mu = sum * (1.f / 512.f);
    float s2 = 0.f;
    #pragma unroll
    for (int u = 0; u < 8; u++) { float d = v[u] - mu; s2 = fmaf(d, d, s2); }
    #pragma unroll
    for (int o = 32; o > 0; o >>= 1) s2 += __shfl_xor(s2, o);
    const float rstd = rsqrtf(s2 * (1.f / 512.f) + 1e-5f);
    #pragma unroll
    for (int u = 0; u < 8; u++) {
        const int c = lane + u * 64;
        float y = (v[u] - mu) * rstd * g[c] + be[c];
        u16 hv = f2bf(y);
        Ohi[(size_t)row * PL + c] = hv;
        Olo[(size_t)row * PL + c] = f2bf(y - bf2f(hv));
    }
}

// ---------------------------------------------------------------------------
// add+LN B: (x1 hi+lo) + (ff hi+lo) -> LN -> sigmoid -> bf16 td. z = layer.
// ---------------------------------------------------------------------------
__global__ __launch_bounds__(256) void add_ln_b(
    const u16* __restrict__ XhiB, const u16* __restrict__ XloB, const size_t xLS,
    const u16* __restrict__ F0h, const u16* __restrict__ F1h,
    const u16* __restrict__ F0l, const u16* __restrict__ F1l,
    const float* __restrict__ g0, const float* __restrict__ g1,
    const float* __restrict__ be0, const float* __restrict__ be1,
    u16* __restrict__ TD0, u16* __restrict__ TD1)
{
    const int z = blockIdx.z;
    const u16* Xhi = XhiB + (size_t)z * xLS;
    const u16* Xlo = XloB + (size_t)z * xLS;
    const u16* Fh = z ? F1h : F0h;
    const u16* Fl = z ? F1l : F0l;
    const float* g = z ? g1 : g0;
    const float* be = z ? be1 : be0;
    u16* TD = z ? TD1 : TD0;
    const int row = blockIdx.x * 4 + (threadIdx.x >> 6);
    const int lane = threadIdx.x & 63;
    const size_t ro = (size_t)row * PL;
    float v[8];
    float sum = 0.f;
    #pragma unroll
    for (int u = 0; u < 8; u++) {
        const int c = lane + u * 64;
        v[u] = bf2f(Xhi[ro + c]) + bf2f(Xlo[ro + c]) + bf2f(Fh[ro + c]) + bf2f(Fl[ro + c]);
        sum += v[u];
    }
    #pragma unroll
    for (int o = 32; o > 0; o >>= 1) sum += __shfl_xor(sum, o);
    const float mu = sum * (1.f / 512.f);
    float s2 = 0.f;
    #pragma unroll
    for (int u = 0; u < 8; u++) { float d = v[u] - mu; s2 = fmaf(d, d, s2); }
    #pragma unroll
    for (int o = 32; o > 0; o >>= 1) s2 += __shfl_xor(s2, o);
    const float rstd = rsqrtf(s2 * (1.f / 512.f) + 1e-5f);
    #pragma unroll
    for (int u = 0; u < 8; u++) {
        const int c = lane + u * 64;
        float y = (v[u] - mu) * rstd * g[c] + be[c];
        TD[ro + c] = f2bf(1.f / (1.f + expf(-y)));
    }
}

// ---------------------------------------------------------------------------
// sim: per batch, C[i][j] = dot(td1[i,:], td2[j,:]) / 512  (plain bf16 MFMA)
// gll-staged, BK=64, counted-vmcnt 2-deep pipeline (8 loads/wave/stage).
// ---------------------------------------------------------------------------
__global__ __launch_bounds__(256) void sim_mfma(const u16* __restrict__ TD1,
    const u16* __restrict__ TD2, float* __restrict__ Out)
{
    __shared__ u16 Ah[2][128 * 64], Bh[2][128 * 64];
    const int t = threadIdx.x, l = t & 63, w = t >> 6;
    const int lr = l & 15, lg = l >> 4;
    const int wm = w >> 1, wn = w & 1;
    const int bz = blockIdx.z;
    const u16* A = TD1 + (size_t)bz * NTOK * PL;
    const u16* B = TD2 + (size_t)bz * NTOK * PL;
    const int m0 = blockIdx.x * 128, n0 = blockIdx.y * 128;

    f32x4 acc[4][4];
    #pragma unroll
    for (int i = 0; i < 4; i++)
        #pragma unroll
        for (int j = 0; j < 4; j++) acc[i][j] = f32x4{0.f, 0.f, 0.f, 0.f};

    auto stage = [&](int bufi, int k0) {
        #pragma unroll
        for (int i = 0; i < 4; i++) {
            const int j = w * 4 + i;
            const int r = j * 8 + (l >> 3);
            const int ck = (l & 7) ^ (r & 7);
            gll16(&A[(size_t)(m0 + r) * 512 + k0 + ck * 8], &Ah[bufi][j * 512]);
            gll16(&B[(size_t)(n0 + r) * 512 + k0 + ck * 8], &Bh[bufi][j * 512]);
        }
    };

    stage(0, 0);
    stage(1, 64);
    for (int kt = 0; kt < 8; kt++) {
        const int buf = kt & 1;
        if (kt < 7) WAITV(8);
        else        WAITV(0);
        __builtin_amdgcn_s_barrier();
        #pragma unroll
        for (int kk = 0; kk < 2; kk++) {
            const int ch = kk * 4 + lg;
            s16x8 af[4], bf[4];
            #pragma unroll
            for (int fm = 0; fm < 4; fm++) {
                const int r = wm * 64 + fm * 16 + lr;
                af[fm] = *(const s16x8*)&Ah[buf][r * 64 + ((ch ^ (r & 7)) << 3)];
            }
            #pragma unroll
            for (int fn = 0; fn < 4; fn++) {
                const int r = wn * 64 + fn * 16 + lr;
                bf[fn] = *(const s16x8*)&Bh[buf][r * 64 + ((ch ^ (r & 7)) << 3)];
            }
            #pragma unroll
            for (int fm = 0; fm < 4; fm++)
                #pragma unroll
                for (int fn = 0; fn < 4; fn++)
                    acc[fm][fn] = __builtin_amdgcn_mfma_f32_16x16x32_bf16(af[fm], bf[fn], acc[fm][fn], 0, 0, 0);
        }
        WAITLGKM;
        __builtin_amdgcn_sched_barrier(0);
        __builtin_amdgcn_s_barrier();
        if (kt < 6) stage(buf, (kt + 2) * 64);
    }
    #pragma unroll
    for (int fm = 0; fm < 4; fm++)
        #pragma unroll
        for (int fn = 0; fn < 4; fn++)
            #pragma unroll
            for (int rg = 0; rg < 4; rg++) {
                const int r = m0 + wm * 64 + fm * 16 + lg * 4 + rg;
                const int c = n0 + wn * 64 + fn * 16 + lr;
                Out[((size_t)(bz * NTOK + r)) * NTOK + c] = acc[fm][fn][rg] * (1.f / 512.f);
            }
}

// ---------------------------------------------------------------------------
extern "C" void kernel_launch(void* const* d_in, const int* in_sizes, int n_in,
                              void* d_out, int out_size, void* d_ws, size_t ws_size,
                              hipStream_t stream)
{
    const float* x = (const float*)d_in[0];
    const float* wqkv[2] = {(const float*)d_in[1],  (const float*)d_in[11]};
    const float* bqkv[2] = {(const float*)d_in[2],  (const float*)d_in[12]};
    const float* ga[2]   = {(const float*)d_in[3],  (const float*)d_in[13]};
    const float* bea[2]  = {(const float*)d_in[4],  (const float*)d_in[14]};
    const float* w1[2]   = {(const float*)d_in[5],  (const float*)d_in[15]};
    const float* b1[2]   = {(const float*)d_in[6],  (const float*)d_in[16]};
    const float* w2[2]   = {(const float*)d_in[7],  (const float*)d_in[17]};
    const float* b2[2]   = {(const float*)d_in[8],  (const float*)d_in[18]};
    const float* gb[2]   = {(const float*)d_in[9],  (const float*)d_in[19]};
    const float* beb[2]  = {(const float*)d_in[10], (const float*)d_in[20]};

    // -------- workspace map (KB offsets; identical to R7/R8 proven layout) --
    char* wsb = (char*)d_ws;
    char* ob  = (char*)d_out;
    #define WSK(kb) ((char*)wsb + ((size_t)(kb) << 10))
    #define OBK(kb) ((char*)ob  + ((size_t)(kb) << 10))
    // ws: [0,4M) wff (S1-S6) -> td1 (S7-)
    u16* w1h = (u16*)WSK(0);      // + z*1048576 elems
    u16* w2h = (u16*)WSK(1024);
    u16* td1 = (u16*)WSK(0);
    // ws: [4M,12M) xsplit (S0-S2) -> AO0 f32 (S3-S4) -> ffo0 hi/lo (S6-S7)
    u16*   xhi  = (u16*)WSK(4096);
    u16*   xlo  = (u16*)WSK(8192);
    float* AO0  = (float*)WSK(4096);
    u16*   ffo0h = (u16*)WSK(4096);
    u16*   ffo0l = (u16*)WSK(8192);
    // ws: [12M,18M) wq hi (S1-S2); [12M,16M) ffo1hi (S6-S7)
    u16* wqh = (u16*)WSK(12288);  // + z*786432 elems
    u16* ffo1h = (u16*)WSK(12288);
    // ws: [16M,32M) x1 hi/lo (S4-S7)
    u16* x1h = (u16*)WSK(16384);  // + z*4194304 elems
    u16* x1l = (u16*)WSK(20480);
    // ws: [18M,34M) Q,K (S2-S3)
    u16* Qb = (u16*)WSK(18432);   // + z*2097152 elems
    u16* Kb = (u16*)WSK(26624);
    // ws: [32M,36M) ffo1lo (S6-S7); [36M,40M) td2 (S7-)
    u16* ffo1l = (u16*)WSK(32768);
    u16* td2   = (u16*)WSK(36864);
    // d_out: Vt (S2-S3); AO1 (S3-S4); h hi/lo (S5-S6); final out (S8)
    u16*   Vt  = (u16*)OBK(0);    // + z*2097152 elems
    float* AO1 = (float*)OBK(8192);
    u16*   h0h = (u16*)OBK(0);
    u16*   h0l = (u16*)OBK(4096);
    u16*   h1h = (u16*)OBK(8192);
    u16*   h1l = (u16*)OBK(12288);
    float* out = (float*)d_out;

    // S0: x split
    convert_x<<<2048, 256, 0, stream>>>(x, xhi, xlo);
    // S1: weight transposes (hi only)
    convert_wt<<<dim3(16, 48, 2), 256, 0, stream>>>(wqkv[0], wqkv[1], wqh, 786432, 1536);
    convert_wt<<<dim3(16, 16, 2), 256, 0, stream>>>(w1[0], w1[1], w1h, 1048576, 512);
    convert_wt<<<dim3(16, 16, 2), 256, 0, stream>>>(w2[0], w2[1], w2h, 1048576, 512);
    // S2: qkv gemm — 2-term (x hi/lo × w-hi), counted-vmcnt pipeline
    gemm_split<128, 0><<<dim3(32, 12, 2), 256, 0, stream>>>(
        xhi, xlo, 0, wqh, 786432, bqkv[0], bqkv[1], 1536,
        Qb, Kb, Vt, nullptr, nullptr, nullptr, nullptr);
    // S3: attention (both layers; z=0 causal, z=1 anti-causal)
    attn_mfma<<<dim3(32, 16, 2), 256, 0, stream>>>(Qb, Kb, Vt, AO0, AO1);
    // S4: add + LN -> x1 hi/lo
    add_ln_a<<<dim3(1024, 1, 2), 256, 0, stream>>>(x, AO0, AO1,
        ga[0], ga[1], bea[0], bea[1], x1h, x1l, 4194304);
    // S5: ff1 (gelu) -> h hi/lo (in d_out)
    gemm_split<64, 1><<<dim3(64, 4, 2), 256, 0, stream>>>(
        x1h, x1l, 4194304, w1h, 1048576, b1[0], b1[1], 512,
        nullptr, nullptr, nullptr, h0h, h1h, h0l, h1l);
    // S6: ff2 -> ffo hi/lo (in ws)
    gemm_split<64, 2><<<dim3(64, 4, 2), 256, 0, stream>>>(
        h0h, h0l, 4194304, w2h, 1048576, b2[0], b2[1], 512,
        nullptr, nullptr, nullptr, ffo0h, ffo1h, ffo0l, ffo1l);
    // S7: add + LN + sigmoid -> td
    add_ln_b<<<dim3(1024, 1, 2), 256, 0, stream>>>(
        x1h, x1l, 4194304, ffo0h, ffo1h, ffo0l, ffo1l,
        gb[0], gb[1], beb[0], beb[1], td1, td2);
    // S8: sim
    sim_mfma<<<dim3(8, 8, 4), 256, 0, stream>>>(td1, td2, out);
}

// Round 10
// 169.363 us; speedup vs baseline: 1.0726x; 1.0726x over previous
//
#include <hip/hip_runtime.h>
#include <math.h>

// ---------------------------------------------------------------------------
// bf16-MFMA implementation, both layers merged (z=2), global_load_lds staging.
//  - all dense GEMMs: 2-term split (A hi/lo × B hi) — R7/R8-proven numerics
//  - R10: qkv GEMM uses PERMUTED weight rows so output is linear [z][4096][1536]
//    (q|k|v, head-slow, dd-fast) -> coalesced epilogue, no scatter.
//    Attention reads Q/K rows directly; V transpose-staged in-kernel.
//  - pipeline: R8 dbuf + __syncthreads (best measured; R9 counted-vmcnt reverted)
// ---------------------------------------------------------------------------

typedef float f32x4 __attribute__((ext_vector_type(4)));
typedef short s16x8 __attribute__((ext_vector_type(8)));
typedef unsigned short u16;
typedef unsigned int u32;

#define NTOK 1024
#define PL 512
#define QSCALE 0.04419417382415922f  // 1/sqrt(512)

__device__ inline u16 f2bf(float f) {
    unsigned u = __builtin_bit_cast(unsigned, f);
    unsigned r = u + 0x7fffu + ((u >> 16) & 1u);   // RNE
    return (u16)(r >> 16);
}
__device__ inline float bf2f(u16 h) {
    unsigned u = ((unsigned)h) << 16;
    return __builtin_bit_cast(float, u);
}

__device__ inline void gll16(const void* g, void* l) {
    __builtin_amdgcn_global_load_lds(
        (const __attribute__((address_space(1))) u32*)g,
        (__attribute__((address_space(3))) u32*)l, 16, 0, 0);
}

// ---------------------------------------------------------------------------
// x -> hi/lo bf16 split (elementwise)
// ---------------------------------------------------------------------------
__global__ __launch_bounds__(256) void convert_x(const float* __restrict__ X,
    u16* __restrict__ hi, u16* __restrict__ lo)
{
    const int i = (blockIdx.x * 256 + threadIdx.x) * 4;
    float4 v = *(const float4*)&X[i];
    float vv[4] = {v.x, v.y, v.z, v.w};
    #pragma unroll
    for (int j = 0; j < 4; j++) {
        u16 h = f2bf(vv[j]);
        hi[i + j] = h;
        lo[i + j] = f2bf(vv[j] - bf2f(h));
    }
}

// ---------------------------------------------------------------------------
// W [512][N] f32 -> Wt [N][512] bf16 hi (tiled transpose), z = layer
// ---------------------------------------------------------------------------
__global__ __launch_bounds__(256) void convert_wt(const float* __restrict__ W0,
    const float* __restrict__ W1, u16* __restrict__ WhiB, const size_t dLS, const int N)
{
    const float* W = blockIdx.z ? W1 : W0;
    u16* Whi = WhiB + (size_t)blockIdx.z * dLS;
    __shared__ float T[32][36];
    const int k0 = blockIdx.x * 32, n0 = blockIdx.y * 32;
    const int tr = threadIdx.x >> 3, tc = (threadIdx.x & 7) * 4;
    *(float4*)&T[tr][tc] = *(const float4*)&W[(size_t)(k0 + tr) * N + n0 + tc];
    __syncthreads();
    const size_t o = (size_t)(n0 + tr) * 512 + k0 + tc;
    #pragma unroll
    for (int j = 0; j < 4; j++) Whi[o + j] = f2bf(T[tc + j][tr]);
}

// π: permuted col j -> original col (head-fast split c2 = dd*8+h)
__device__ inline int qkv_perm(int j) {
    return (j >> 9) * 512 + ((j & 63) << 3) + ((j >> 6) & 7);
}

// ---------------------------------------------------------------------------
// 2-term split-bf16 MFMA GEMM, z = layer. A[4096][512] (hi/lo) x Bt[N][512] (hi).
// EPI: 0 = qkv (B rows permuted, linear [z*4096+r][1536] output, Q scaled),
//      1 = gelu -> hi/lo, 2 = plain hi/lo.
// BK=32; dbuf gll staging (stage kt+1 before compute kt, 1 barrier).
// ---------------------------------------------------------------------------
template<int BM, int EPI>
__global__ __launch_bounds__(256) void gemm_split(
    const u16* __restrict__ AhiB, const u16* __restrict__ AloB, const size_t aLS,
    const u16* __restrict__ BhiB, const size_t bLS,
    const float* __restrict__ bias0, const float* __restrict__ bias1, const int Ncols,
    u16* __restrict__ oh0, u16* __restrict__ oh1,
    u16* __restrict__ ol0, u16* __restrict__ ol1)
{
    constexpr int FM = BM / 32;
    __shared__ u16 Ah[2][BM * 32], Al[2][BM * 32], Bh[2][128 * 32];
    const int z = blockIdx.z;
    const u16* Ahi = AhiB + (size_t)z * aLS;
    const u16* Alo = AloB + (size_t)z * aLS;
    const u16* Bhi = BhiB + (size_t)z * bLS;
    const float* bias = z ? bias1 : bias0;
    u16* oh = z ? oh1 : oh0;
    u16* ol = z ? ol1 : ol0;

    const int t = threadIdx.x, l = t & 63, w = t >> 6;
    const int lr = l & 15, lg = l >> 4;
    const int wm = w >> 1, wn = w & 1;
    const int m0 = blockIdx.x * BM, n0 = blockIdx.y * 128;
    const int srow = l >> 2, sch = l & 3;    // staging lane coords (16 rows/KB)

    f32x4 acc[FM][4];
    #pragma unroll
    for (int i = 0; i < FM; i++)
        #pragma unroll
        for (int j = 0; j < 4; j++) acc[i][j] = f32x4{0.f, 0.f, 0.f, 0.f};

    auto stage = [&](int bufi, int k0) {
        #pragma unroll
        for (int i = 0; i < BM / 64; i++) {
            const int j = w * (BM / 64) + i;
            const int r = j * 16 + srow;
            const int ck = sch ^ ((r >> 1) & 3);
            const size_t g = (size_t)(m0 + r) * 512 + k0 + ck * 8;
            gll16(&Ahi[g], &Ah[bufi][j * 512]);
            gll16(&Alo[g], &Al[bufi][j * 512]);
        }
        #pragma unroll
        for (int i = 0; i < 2; i++) {
            const int j = w * 2 + i;
            const int r = j * 16 + srow;
            const int ck = sch ^ ((r >> 1) & 3);
            const int brow = (EPI == 0) ? qkv_perm(n0 + r) : (n0 + r);
            gll16(&Bhi[(size_t)brow * 512 + k0 + ck * 8], &Bh[bufi][j * 512]);
        }
    };

    stage(0, 0);
    __syncthreads();
    int buf = 0;
    for (int kt = 0; kt < 16; kt++) {
        if (kt < 15) stage(buf ^ 1, (kt + 1) * 32);

        s16x8 ah[FM], al[FM];
        #pragma unroll
        for (int fm = 0; fm < FM; fm++) {
            const int r = wm * (BM / 2) + fm * 16 + lr;
            const int d = r * 32 + ((lg ^ ((r >> 1) & 3)) << 3);
            ah[fm] = *(const s16x8*)&Ah[buf][d];
            al[fm] = *(const s16x8*)&Al[buf][d];
        }
        #pragma unroll
        for (int fn = 0; fn < 4; fn++) {
            const int r = wn * 64 + fn * 16 + lr;
            const int d = r * 32 + ((lg ^ ((r >> 1) & 3)) << 3);
            s16x8 bh = *(const s16x8*)&Bh[buf][d];
            #pragma unroll
            for (int fm = 0; fm < FM; fm++) {
                acc[fm][fn] = __builtin_amdgcn_mfma_f32_16x16x32_bf16(ah[fm], bh, acc[fm][fn], 0, 0, 0);
                acc[fm][fn] = __builtin_amdgcn_mfma_f32_16x16x32_bf16(al[fm], bh, acc[fm][fn], 0, 0, 0);
            }
        }
        __syncthreads();   // waves done with buf; stage(buf^1) drained
        buf ^= 1;
    }
    // epilogue
    #pragma unroll
    for (int fm = 0; fm < FM; fm++)
        #pragma unroll
        for (int fn = 0; fn < 4; fn++)
            #pragma unroll
            for (int rg = 0; rg < 4; rg++) {
                const int r = m0 + wm * (BM / 2) + fm * 16 + lg * 4 + rg;
                const int c = n0 + wn * 64 + fn * 16 + lr;
                if constexpr (EPI == 0) {
                    float v = acc[fm][fn][rg] + bias[qkv_perm(c)];
                    if (c < 512) v *= QSCALE;   // Q third (uniform per block)
                    oh[((size_t)z * 4096 + r) * Ncols + c] = f2bf(v);
                } else {
                    float gl = acc[fm][fn][rg] + bias[c];
                    if constexpr (EPI == 1)
                        gl = 0.5f * gl * (1.f + erff(gl * 0.70710678118654752f));
                    u16 hv = f2bf(gl);
                    oh[(size_t)r * Ncols + c] = hv;
                    ol[(size_t)r * Ncols + c] = f2bf(gl - bf2f(hv));
                }
            }
}

// ---------------------------------------------------------------------------
// Flash attention, bf16 MFMA, z = layer (z==0 causal, z==1 anti-causal).
// Reads qkvB [z][4096][1536] (q|k|v, head-slow). K gll-staged (dbuf);
// V transpose-staged: reg loads issued with prefetch, swizzled ds_write_b16
// before the barrier (T14 issue-early/write-late).
// ---------------------------------------------------------------------------
__global__ __launch_bounds__(256) void attn_mfma(const u16* __restrict__ QKV,
    float* __restrict__ AO0, float* __restrict__ AO1)
{
    __shared__ u16 Ks[2][64 * 64];
    __shared__ u16 Vs[2][64 * 64];
    __shared__ u16 Ps[4][16 * 72];
    const int t = threadIdx.x, l = t & 63, w = t >> 6;
    const int lr = l & 15, lg = l >> 4;
    const int z = blockIdx.z;
    const int causal = (z == 0);
    const int bh = blockIdx.x;
    const int b = bh >> 3, h = bh & 7;
    const int qt = causal ? (15 - (int)blockIdx.y) : (int)blockIdx.y;  // long jobs first
    const u16* base = QKV + ((size_t)z * 4096 + (size_t)b * NTOK) * 1536;
    float* AO = z ? AO1 : AO0;
    const int q0 = qt * 64 + w * 16;

    // Q fragments (row-major read from qkv buffer)
    s16x8 aq[2];
    aq[0] = *(const s16x8*)&base[(size_t)(q0 + lr) * 1536 + h * 64 + lg * 8];
    aq[1] = *(const s16x8*)&base[(size_t)(q0 + lr) * 1536 + h * 64 + 32 + lg * 8];

    f32x4 o[4];
    float m_[4], l_[4];
    #pragma unroll
    for (int f = 0; f < 4; f++) o[f] = f32x4{0.f, 0.f, 0.f, 0.f};
    #pragma unroll
    for (int r = 0; r < 4; r++) { m_[r] = -INFINITY; l_[r] = 0.f; }

    const int kt0 = causal ? 0 : qt, kt1 = causal ? qt : 15;

    auto stageK = [&](int bufi, int kt) {
        #pragma unroll
        for (int i = 0; i < 2; i++) {
            const int j = w * 2 + i;
            const int r = j * 8 + (l >> 3);
            const int ck = (l & 7) ^ (r & 7);
            gll16(&base[(size_t)(kt * 64 + r) * 1536 + 512 + h * 64 + ck * 8],
                  &Ks[bufi][j * 512]);
        }
    };
    // V tile: thread covers key row jv = t&63, dims d = w*16 + 0..15
    const int jv = t & 63;
    s16x8 va, vb;
    auto loadV = [&](int kt) {
        const u16* vr = &base[(size_t)(kt * 64 + jv) * 1536 + 1024 + h * 64 + w * 16];
        va = *(const s16x8*)&vr[0];
        vb = *(const s16x8*)&vr[8];
    };
    auto writeV = [&](int bufi) {
        #pragma unroll
        for (int i = 0; i < 8; i++) {
            const int d = w * 16 + i;
            Vs[bufi][d * 64 + (((jv >> 3) ^ (d & 7)) << 3) + (jv & 7)] = (u16)va[i];
        }
        #pragma unroll
        for (int i = 0; i < 8; i++) {
            const int d = w * 16 + 8 + i;
            Vs[bufi][d * 64 + (((jv >> 3) ^ (d & 7)) << 3) + (jv & 7)] = (u16)vb[i];
        }
    };

    stageK(0, kt0);
    loadV(kt0);
    writeV(0);           // compiler inserts vmcnt wait for va/vb
    __syncthreads();     // drains K glls + ds_writes
    int buf = 0;
    for (int kt = kt0; kt <= kt1; kt++) {
        if (kt < kt1) { stageK(buf ^ 1, kt + 1); loadV(kt + 1); }
        // ---- S = Q K^T ----
        f32x4 s[4];
        #pragma unroll
        for (int f = 0; f < 4; f++) s[f] = f32x4{0.f, 0.f, 0.f, 0.f};
        #pragma unroll
        for (int kk = 0; kk < 2; kk++)
            #pragma unroll
            for (int f = 0; f < 4; f++) {
                const int row = f * 16 + lr;
                const int ch = kk * 4 + lg;
                s16x8 bk = *(const s16x8*)&Ks[buf][row * 64 + ((ch ^ (row & 7)) << 3)];
                s[f] = __builtin_amdgcn_mfma_f32_16x16x32_bf16(aq[kk], bk, s[f], 0, 0, 0);
            }
        if (kt == qt) {
            #pragma unroll
            for (int f = 0; f < 4; f++) {
                const int key = kt * 64 + f * 16 + lr;
                #pragma unroll
                for (int r = 0; r < 4; r++) {
                    const int q = q0 + lg * 4 + r;
                    if (causal ? (key > q) : (key < q)) s[f][r] = -INFINITY;
                }
            }
        }
        float scale[4];
        #pragma unroll
        for (int r = 0; r < 4; r++) {
            float rm = fmaxf(fmaxf(s[0][r], s[1][r]), fmaxf(s[2][r], s[3][r]));
            #pragma unroll
            for (int off = 1; off < 16; off <<= 1) rm = fmaxf(rm, __shfl_xor(rm, off));
            const float mn = fmaxf(m_[r], rm);
            scale[r] = __expf(m_[r] - mn);
            float ps = 0.f;
            #pragma unroll
            for (int f = 0; f < 4; f++) { float p = __expf(s[f][r] - mn); s[f][r] = p; ps += p; }
            #pragma unroll
            for (int off = 1; off < 16; off <<= 1) ps += __shfl_xor(ps, off);
            l_[r] = l_[r] * scale[r] + ps;
            m_[r] = mn;
        }
        #pragma unroll
        for (int f = 0; f < 4; f++)
            #pragma unroll
            for (int r = 0; r < 4; r++)
                Ps[w][(lg * 4 + r) * 72 + f * 16 + lr] = f2bf(s[f][r]);
        #pragma unroll
        for (int f = 0; f < 4; f++)
            #pragma unroll
            for (int r = 0; r < 4; r++) o[f][r] *= scale[r];
        #pragma unroll
        for (int kk = 0; kk < 2; kk++) {
            s16x8 ap = *(const s16x8*)&Ps[w][lr * 72 + kk * 32 + lg * 8];
            #pragma unroll
            for (int f = 0; f < 4; f++) {
                const int row = f * 16 + lr;
                const int ch = kk * 4 + lg;
                s16x8 bv = *(const s16x8*)&Vs[buf][row * 64 + ((ch ^ (row & 7)) << 3)];
                o[f] = __builtin_amdgcn_mfma_f32_16x16x32_bf16(ap, bv, o[f], 0, 0, 0);
            }
        }
        if (kt < kt1) writeV(buf ^ 1);   // before barrier -> visible next iter
        __syncthreads();
        buf ^= 1;
    }
    #pragma unroll
    for (int f = 0; f < 4; f++)
        #pragma unroll
        for (int r = 0; r < 4; r++)
            AO[(size_t)(b * NTOK + q0 + lg * 4 + r) * PL + h * 64 + f * 16 + lr] = o[f][r] / l_[r];
}

// ---------------------------------------------------------------------------
// add+LN A: x(f32)+attn(f32) -> LN -> hi/lo bf16. z = layer.
// ---------------------------------------------------------------------------
__global__ __launch_bounds__(256) void add_ln_a(const float* __restrict__ X,
    const float* __restrict__ A0, const float* __restrict__ A1,
    const float* __restrict__ g0, const float* __restrict__ g1,
    const float* __restrict__ be0, const float* __restrict__ be1,
    u16* __restrict__ OhiB, u16* __restrict__ OloB, const size_t oLS)
{
    const int z = blockIdx.z;
    const float* A = z ? A1 : A0;
    const float* g = z ? g1 : g0;
    const float* be = z ? be1 : be0;
    u16* Ohi = OhiB + (size_t)z * oLS;
    u16* Olo = OloB + (size_t)z * oLS;
    const int row = blockIdx.x * 4 + (threadIdx.x >> 6);
    const int lane = threadIdx.x & 63;
    const float* xr = X + (size_t)row * PL;
    const float* ar = A + (size_t)row * PL;
    float v[8];
    float sum = 0.f;
    #pragma unroll
    for (int u = 0; u < 8; u++) { v[u] = xr[lane + u * 64] + ar[lane + u * 64]; sum += v[u]; }
    #pragma unroll
    for (int o = 32; o > 0; o >>= 1) sum += __shfl_xor(sum, o);
    const float mu = sum * (1.f / 512.f);
    float s2 = 0.f;
    #pragma unroll
    for (int u = 0; u < 8; u++) { float d = v[u] - mu; s2 = fmaf(d, d, s2); }
    #pragma unroll
    for (int o = 32; o > 0; o >>= 1) s2 += __shfl_xor(s2, o);
    const float rstd = rsqrtf(s2 * (1.f / 512.f) + 1e-5f);
    #pragma unroll
    for (int u = 0; u < 8; u++) {
        const int c = lane + u * 64;
        float y = (v[u] - mu) * rstd * g[c] + be[c];
        u16 hv = f2bf(y);
        Ohi[(size_t)row * PL + c] = hv;
        Olo[(size_t)row * PL + c] = f2bf(y - bf2f(hv));
    }
}

// ---------------------------------------------------------------------------
// add+LN B: (x1 hi+lo) + (ff hi+lo) -> LN -> sigmoid -> bf16 td. z = layer.
// ---------------------------------------------------------------------------
__global__ __launch_bounds__(256) void add_ln_b(
    const u16* __restrict__ XhiB, const u16* __restrict__ XloB, const size_t xLS,
    const u16* __restrict__ F0h, const u16* __restrict__ F1h,
    const u16* __restrict__ F0l, const u16* __restrict__ F1l,
    const float* __restrict__ g0, const float* __restrict__ g1,
    const float* __restrict__ be0, const float* __restrict__ be1,
    u16* __restrict__ TD0, u16* __restrict__ TD1)
{
    const int z = blockIdx.z;
    const u16* Xhi = XhiB + (size_t)z * xLS;
    const u16* Xlo = XloB + (size_t)z * xLS;
    const u16* Fh = z ? F1h : F0h;
    const u16* Fl = z ? F1l : F0l;
    const float* g = z ? g1 : g0;
    const float* be = z ? be1 : be0;
    u16* TD = z ? TD1 : TD0;
    const int row = blockIdx.x * 4 + (threadIdx.x >> 6);
    const int lane = threadIdx.x & 63;
    const size_t ro = (size_t)row * PL;
    float v[8];
    float sum = 0.f;
    #pragma unroll
    for (int u = 0; u < 8; u++) {
        const int c = lane + u * 64;
        v[u] = bf2f(Xhi[ro + c]) + bf2f(Xlo[ro + c]) + bf2f(Fh[ro + c]) + bf2f(Fl[ro + c]);
        sum += v[u];
    }
    #pragma unroll
    for (int o = 32; o > 0; o >>= 1) sum += __shfl_xor(sum, o);
    const float mu = sum * (1.f / 512.f);
    float s2 = 0.f;
    #pragma unroll
    for (int u = 0; u < 8; u++) { float d = v[u] - mu; s2 = fmaf(d, d, s2); }
    #pragma unroll
    for (int o = 32; o > 0; o >>= 1) s2 += __shfl_xor(s2, o);
    const float rstd = rsqrtf(s2 * (1.f / 512.f) + 1e-5f);
    #pragma unroll
    for (int u = 0; u < 8; u++) {
        const int c = lane + u * 64;
        float y = (v[u] - mu) * rstd * g[c] + be[c];
        TD[ro + c] = f2bf(1.f / (1.f + expf(-y)));
    }
}

// ---------------------------------------------------------------------------
// sim: per batch, C[i][j] = dot(td1[i,:], td2[j,:]) / 512  (plain bf16 MFMA)
// gll-staged, BK=64, dbuf (R8 form).
// ---------------------------------------------------------------------------
__global__ __launch_bounds__(256) void sim_mfma(const u16* __restrict__ TD1,
    const u16* __restrict__ TD2, float* __restrict__ Out)
{
    __shared__ u16 Ah[2][128 * 64], Bh[2][128 * 64];
    const int t = threadIdx.x, l = t & 63, w = t >> 6;
    const int lr = l & 15, lg = l >> 4;
    const int wm = w >> 1, wn = w & 1;
    const int bz = blockIdx.z;
    const u16* A = TD1 + (size_t)bz * NTOK * PL;
    const u16* B = TD2 + (size_t)bz * NTOK * PL;
    const int m0 = blockIdx.x * 128, n0 = blockIdx.y * 128;

    f32x4 acc[4][4];
    #pragma unroll
    for (int i = 0; i < 4; i++)
        #pragma unroll
        for (int j = 0; j < 4; j++) acc[i][j] = f32x4{0.f, 0.f, 0.f, 0.f};

    auto stage = [&](int bufi, int k0) {
        #pragma unroll
        for (int i = 0; i < 4; i++) {
            const int j = w * 4 + i;
            const int r = j * 8 + (l >> 3);
            const int ck = (l & 7) ^ (r & 7);
            gll16(&A[(size_t)(m0 + r) * 512 + k0 + ck * 8], &Ah[bufi][j * 512]);
            gll16(&B[(size_t)(n0 + r) * 512 + k0 + ck * 8], &Bh[bufi][j * 512]);
        }
    };

    stage(0, 0);
    __syncthreads();
    int buf = 0;
    for (int kt = 0; kt < 8; kt++) {
        if (kt < 7) stage(buf ^ 1, (kt + 1) * 64);
        #pragma unroll
        for (int kk = 0; kk < 2; kk++) {
            const int ch = kk * 4 + lg;
            s16x8 af[4], bf[4];
            #pragma unroll
            for (int fm = 0; fm < 4; fm++) {
                const int r = wm * 64 + fm * 16 + lr;
                af[fm] = *(const s16x8*)&Ah[buf][r * 64 + ((ch ^ (r & 7)) << 3)];
            }
            #pragma unroll
            for (int fn = 0; fn < 4; fn++) {
                const int r = wn * 64 + fn * 16 + lr;
                bf[fn] = *(const s16x8*)&Bh[buf][r * 64 + ((ch ^ (r & 7)) << 3)];
            }
            #pragma unroll
            for (int fm = 0; fm < 4; fm++)
                #pragma unroll
                for (int fn = 0; fn < 4; fn++)
                    acc[fm][fn] = __builtin_amdgcn_mfma_f32_16x16x32_bf16(af[fm], bf[fn], acc[fm][fn], 0, 0, 0);
        }
        __syncthreads();
        buf ^= 1;
    }
    #pragma unroll
    for (int fm = 0; fm < 4; fm++)
        #pragma unroll
        for (int fn = 0; fn < 4; fn++)
            #pragma unroll
            for (int rg = 0; rg < 4; rg++) {
                const int r = m0 + wm * 64 + fm * 16 + lg * 4 + rg;
                const int c = n0 + wn * 64 + fn * 16 + lr;
                Out[((size_t)(bz * NTOK + r)) * NTOK + c] = acc[fm][fn][rg] * (1.f / 512.f);
            }
}

// ---------------------------------------------------------------------------
extern "C" void kernel_launch(void* const* d_in, const int* in_sizes, int n_in,
                              void* d_out, int out_size, void* d_ws, size_t ws_size,
                              hipStream_t stream)
{
    const float* x = (const float*)d_in[0];
    const float* wqkv[2] = {(const float*)d_in[1],  (const float*)d_in[11]};
    const float* bqkv[2] = {(const float*)d_in[2],  (const float*)d_in[12]};
    const float* ga[2]   = {(const float*)d_in[3],  (const float*)d_in[13]};
    const float* bea[2]  = {(const float*)d_in[4],  (const float*)d_in[14]};
    const float* w1[2]   = {(const float*)d_in[5],  (const float*)d_in[15]};
    const float* b1[2]   = {(const float*)d_in[6],  (const float*)d_in[16]};
    const float* w2[2]   = {(const float*)d_in[7],  (const float*)d_in[17]};
    const float* b2[2]   = {(const float*)d_in[8],  (const float*)d_in[18]};
    const float* gb[2]   = {(const float*)d_in[9],  (const float*)d_in[19]};
    const float* beb[2]  = {(const float*)d_in[10], (const float*)d_in[20]};

    // -------- workspace map (KB offsets; lifetimes verified stage-by-stage) --
    char* wsb = (char*)d_ws;
    char* ob  = (char*)d_out;
    #define WSK(kb) ((char*)wsb + ((size_t)(kb) << 10))
    #define OBK(kb) ((char*)ob  + ((size_t)(kb) << 10))
    // ws [0,8M):  xhi/xlo (S0-S2)  -> x1h z0/z1 (S4-S7)
    u16* xhi = (u16*)WSK(0);
    u16* xlo = (u16*)WSK(4096);
    u16* x1h = (u16*)WSK(0);          // + z*2097152 elems
    // ws [8,11M): wqh (S1-S2) -> td1 ws[8,12) (S7-)
    u16* wqh = (u16*)WSK(8192);       // + z*786432 elems
    u16* td1 = (u16*)WSK(8192);
    // ws [11,13M): w1h, w2h (S1-S6); td2 ws[12,16) (S7-)
    u16* w1h = (u16*)WSK(11264);      // + z*262144 elems
    u16* w2h = (u16*)WSK(12288);      // + z*262144 elems
    u16* td2 = (u16*)WSK(12288);
    // ws [13,37M): qkvB (S2-S3)
    u16* qkvB = (u16*)WSK(13312);     // [z][4096][1536]
    // ws [16,24M): x1l z0/z1 (S4-S7)
    u16* x1l = (u16*)WSK(16384);      // + z*2097152 elems
    // ws [24,40M): ffo hi/lo (S6-S7)
    u16* ffo0h = (u16*)WSK(24576);
    u16* ffo0l = (u16*)WSK(28672);
    u16* ffo1h = (u16*)WSK(32768);
    u16* ffo1l = (u16*)WSK(36864);
    // d_out: AO0/AO1 f32 (S3-S4); h hi/lo (S5-S6); final out (S8)
    float* AO0 = (float*)OBK(0);
    float* AO1 = (float*)OBK(8192);
    u16* h0h = (u16*)OBK(0);
    u16* h0l = (u16*)OBK(4096);
    u16* h1h = (u16*)OBK(8192);
    u16* h1l = (u16*)OBK(12288);
    float* out = (float*)d_out;

    // S0: x split
    convert_x<<<2048, 256, 0, stream>>>(x, xhi, xlo);
    // S1: weight transposes (hi only)
    convert_wt<<<dim3(16, 48, 2), 256, 0, stream>>>(wqkv[0], wqkv[1], wqh, 786432, 1536);
    convert_wt<<<dim3(16, 16, 2), 256, 0, stream>>>(w1[0], w1[1], w1h, 262144, 512);
    convert_wt<<<dim3(16, 16, 2), 256, 0, stream>>>(w2[0], w2[1], w2h, 262144, 512);
    // S2: qkv gemm — permuted-B, linear output into qkvB
    gemm_split<128, 0><<<dim3(32, 12, 2), 256, 0, stream>>>(
        xhi, xlo, 0, wqh, 786432, bqkv[0], bqkv[1], 1536,
        qkvB, qkvB, nullptr, nullptr);
    // S3: attention (z=0 causal, z=1 anti-causal)
    attn_mfma<<<dim3(32, 16, 2), 256, 0, stream>>>(qkvB, AO0, AO1);
    // S4: add + LN -> x1 hi/lo
    add_ln_a<<<dim3(1024, 1, 2), 256, 0, stream>>>(x, AO0, AO1,
        ga[0], ga[1], bea[0], bea[1], x1h, x1l, 2097152);
    // S5: ff1 (gelu) -> h hi/lo (in d_out)
    gemm_split<64, 1><<<dim3(64, 4, 2), 256, 0, stream>>>(
        x1h, x1l, 2097152, w1h, 262144, b1[0], b1[1], 512,
        h0h, h1h, h0l, h1l);
    // S6: ff2 -> ffo hi/lo (in ws)
    gemm_split<64, 2><<<dim3(64, 4, 2), 256, 0, stream>>>(
        h0h, h0l, 2097152, w2h, 262144, b2[0], b2[1], 512,
        ffo0h, ffo1h, ffo0l, ffo1l);
    // S7: add + LN + sigmoid -> td
    add_ln_b<<<dim3(1024, 1, 2), 256, 0, stream>>>(
        x1h, x1l, 2097152, ffo0h, ffo1h, ffo0l, ffo1l,
        gb[0], gb[1], beb[0], beb[1], td1, td2);
    // S8: sim
    sim_mfma<<<dim3(8, 8, 4), 256, 0, stream>>>(td1, td2, out);
}

// Round 11
// 162.124 us; speedup vs baseline: 1.1204x; 1.0447x over previous
//
#include <hip/hip_runtime.h>
#include <math.h>

// ---------------------------------------------------------------------------
// bf16-MFMA implementation, both layers merged (z=2), global_load_lds staging.
//  - all dense GEMMs: 2-term split (A hi/lo × B hi) — R7/R8-proven numerics
//  - R10: qkv linear [z][4096][1536] output via permuted weight rows
//  - R11: attention swapped-QK^T (S^T = K·Q^T): softmax lane-local (2 shfl),
//    P stays in registers (cvt_pk + bpermute redistribution), Ps LDS removed
//    (42->32KB, 4 blocks/CU). Only attn_mfma changed vs R10.
// ---------------------------------------------------------------------------

typedef float f32x4 __attribute__((ext_vector_type(4)));
typedef short s16x8 __attribute__((ext_vector_type(8)));
typedef int   i32x4 __attribute__((ext_vector_type(4)));
typedef unsigned short u16;
typedef unsigned int u32;

#define NTOK 1024
#define PL 512
#define QSCALE 0.04419417382415922f  // 1/sqrt(512)

__device__ inline u16 f2bf(float f) {
    unsigned u = __builtin_bit_cast(unsigned, f);
    unsigned r = u + 0x7fffu + ((u >> 16) & 1u);   // RNE
    return (u16)(r >> 16);
}
__device__ inline float bf2f(u16 h) {
    unsigned u = ((unsigned)h) << 16;
    return __builtin_bit_cast(float, u);
}
__device__ inline u32 cvtpk(float a, float b) {   // lo=a, hi=b (RNE)
    u32 r;
    asm("v_cvt_pk_bf16_f32 %0, %1, %2" : "=v"(r) : "v"(a), "v"(b));
    return r;
}

__device__ inline void gll16(const void* g, void* l) {
    __builtin_amdgcn_global_load_lds(
        (const __attribute__((address_space(1))) u32*)g,
        (__attribute__((address_space(3))) u32*)l, 16, 0, 0);
}

// ---------------------------------------------------------------------------
// x -> hi/lo bf16 split (elementwise)
// ---------------------------------------------------------------------------
__global__ __launch_bounds__(256) void convert_x(const float* __restrict__ X,
    u16* __restrict__ hi, u16* __restrict__ lo)
{
    const int i = (blockIdx.x * 256 + threadIdx.x) * 4;
    float4 v = *(const float4*)&X[i];
    float vv[4] = {v.x, v.y, v.z, v.w};
    #pragma unroll
    for (int j = 0; j < 4; j++) {
        u16 h = f2bf(vv[j]);
        hi[i + j] = h;
        lo[i + j] = f2bf(vv[j] - bf2f(h));
    }
}

// ---------------------------------------------------------------------------
// W [512][N] f32 -> Wt [N][512] bf16 hi (tiled transpose), z = layer
// ---------------------------------------------------------------------------
__global__ __launch_bounds__(256) void convert_wt(const float* __restrict__ W0,
    const float* __restrict__ W1, u16* __restrict__ WhiB, const size_t dLS, const int N)
{
    const float* W = blockIdx.z ? W1 : W0;
    u16* Whi = WhiB + (size_t)blockIdx.z * dLS;
    __shared__ float T[32][36];
    const int k0 = blockIdx.x * 32, n0 = blockIdx.y * 32;
    const int tr = threadIdx.x >> 3, tc = (threadIdx.x & 7) * 4;
    *(float4*)&T[tr][tc] = *(const float4*)&W[(size_t)(k0 + tr) * N + n0 + tc];
    __syncthreads();
    const size_t o = (size_t)(n0 + tr) * 512 + k0 + tc;
    #pragma unroll
    for (int j = 0; j < 4; j++) Whi[o + j] = f2bf(T[tc + j][tr]);
}

// π: permuted col j -> original col (head-fast split c2 = dd*8+h)
__device__ inline int qkv_perm(int j) {
    return (j >> 9) * 512 + ((j & 63) << 3) + ((j >> 6) & 7);
}

// ---------------------------------------------------------------------------
// 2-term split-bf16 MFMA GEMM, z = layer. A[4096][512] (hi/lo) x Bt[N][512] (hi).
// EPI: 0 = qkv (B rows permuted, linear [z*4096+r][1536] output, Q scaled),
//      1 = gelu -> hi/lo, 2 = plain hi/lo.
// BK=32; dbuf gll staging (stage kt+1 before compute kt, 1 barrier).
// ---------------------------------------------------------------------------
template<int BM, int EPI>
__global__ __launch_bounds__(256) void gemm_split(
    const u16* __restrict__ AhiB, const u16* __restrict__ AloB, const size_t aLS,
    const u16* __restrict__ BhiB, const size_t bLS,
    const float* __restrict__ bias0, const float* __restrict__ bias1, const int Ncols,
    u16* __restrict__ oh0, u16* __restrict__ oh1,
    u16* __restrict__ ol0, u16* __restrict__ ol1)
{
    constexpr int FM = BM / 32;
    __shared__ u16 Ah[2][BM * 32], Al[2][BM * 32], Bh[2][128 * 32];
    const int z = blockIdx.z;
    const u16* Ahi = AhiB + (size_t)z * aLS;
    const u16* Alo = AloB + (size_t)z * aLS;
    const u16* Bhi = BhiB + (size_t)z * bLS;
    const float* bias = z ? bias1 : bias0;
    u16* oh = z ? oh1 : oh0;
    u16* ol = z ? ol1 : ol0;

    const int t = threadIdx.x, l = t & 63, w = t >> 6;
    const int lr = l & 15, lg = l >> 4;
    const int wm = w >> 1, wn = w & 1;
    const int m0 = blockIdx.x * BM, n0 = blockIdx.y * 128;
    const int srow = l >> 2, sch = l & 3;    // staging lane coords (16 rows/KB)

    f32x4 acc[FM][4];
    #pragma unroll
    for (int i = 0; i < FM; i++)
        #pragma unroll
        for (int j = 0; j < 4; j++) acc[i][j] = f32x4{0.f, 0.f, 0.f, 0.f};

    auto stage = [&](int bufi, int k0) {
        #pragma unroll
        for (int i = 0; i < BM / 64; i++) {
            const int j = w * (BM / 64) + i;
            const int r = j * 16 + srow;
            const int ck = sch ^ ((r >> 1) & 3);
            const size_t g = (size_t)(m0 + r) * 512 + k0 + ck * 8;
            gll16(&Ahi[g], &Ah[bufi][j * 512]);
            gll16(&Alo[g], &Al[bufi][j * 512]);
        }
        #pragma unroll
        for (int i = 0; i < 2; i++) {
            const int j = w * 2 + i;
            const int r = j * 16 + srow;
            const int ck = sch ^ ((r >> 1) & 3);
            const int brow = (EPI == 0) ? qkv_perm(n0 + r) : (n0 + r);
            gll16(&Bhi[(size_t)brow * 512 + k0 + ck * 8], &Bh[bufi][j * 512]);
        }
    };

    stage(0, 0);
    __syncthreads();
    int buf = 0;
    for (int kt = 0; kt < 16; kt++) {
        if (kt < 15) stage(buf ^ 1, (kt + 1) * 32);

        s16x8 ah[FM], al[FM];
        #pragma unroll
        for (int fm = 0; fm < FM; fm++) {
            const int r = wm * (BM / 2) + fm * 16 + lr;
            const int d = r * 32 + ((lg ^ ((r >> 1) & 3)) << 3);
            ah[fm] = *(const s16x8*)&Ah[buf][d];
            al[fm] = *(const s16x8*)&Al[buf][d];
        }
        #pragma unroll
        for (int fn = 0; fn < 4; fn++) {
            const int r = wn * 64 + fn * 16 + lr;
            const int d = r * 32 + ((lg ^ ((r >> 1) & 3)) << 3);
            s16x8 bh = *(const s16x8*)&Bh[buf][d];
            #pragma unroll
            for (int fm = 0; fm < FM; fm++) {
                acc[fm][fn] = __builtin_amdgcn_mfma_f32_16x16x32_bf16(ah[fm], bh, acc[fm][fn], 0, 0, 0);
                acc[fm][fn] = __builtin_amdgcn_mfma_f32_16x16x32_bf16(al[fm], bh, acc[fm][fn], 0, 0, 0);
            }
        }
        __syncthreads();   // waves done with buf; stage(buf^1) drained
        buf ^= 1;
    }
    // epilogue
    #pragma unroll
    for (int fm = 0; fm < FM; fm++)
        #pragma unroll
        for (int fn = 0; fn < 4; fn++)
            #pragma unroll
            for (int rg = 0; rg < 4; rg++) {
                const int r = m0 + wm * (BM / 2) + fm * 16 + lg * 4 + rg;
                const int c = n0 + wn * 64 + fn * 16 + lr;
                if constexpr (EPI == 0) {
                    float v = acc[fm][fn][rg] + bias[qkv_perm(c)];
                    if (c < 512) v *= QSCALE;   // Q third (uniform per block)
                    oh[((size_t)z * 4096 + r) * Ncols + c] = f2bf(v);
                } else {
                    float gl = acc[fm][fn][rg] + bias[c];
                    if constexpr (EPI == 1)
                        gl = 0.5f * gl * (1.f + erff(gl * 0.70710678118654752f));
                    u16 hv = f2bf(gl);
                    oh[(size_t)r * Ncols + c] = hv;
                    ol[(size_t)r * Ncols + c] = f2bf(gl - bf2f(hv));
                }
            }
}

// ---------------------------------------------------------------------------
// Flash attention, bf16 MFMA, z = layer (z==0 causal, z==1 anti-causal).
// R11: swapped QK^T (S^T = mfma(K,Q)) -> lane-local softmax (2 shfl);
// P packed in-register (cvt_pk) and redistributed to the PV A-frag via
// 16 bpermute + 8 selects. No Ps LDS. K gll-staged dbuf; V transpose-staged.
// ---------------------------------------------------------------------------
__global__ __launch_bounds__(256) void attn_mfma(const u16* __restrict__ QKV,
    float* __restrict__ AO0, float* __restrict__ AO1)
{
    __shared__ u16 Ks[2][64 * 64];
    __shared__ u16 Vs[2][64 * 64];
    const int t = threadIdx.x, l = t & 63, w = t >> 6;
    const int lr = l & 15, lg = l >> 4;
    const int z = blockIdx.z;
    const int causal = (z == 0);
    const int bh = blockIdx.x;
    const int b = bh >> 3, h = bh & 7;
    const int qt = causal ? (15 - (int)blockIdx.y) : (int)blockIdx.y;  // long jobs first
    const u16* base = QKV + ((size_t)z * 4096 + (size_t)b * NTOK) * 1536;
    float* AO = z ? AO1 : AO0;
    const int q0 = qt * 64 + w * 16;

    // Q fragments (used as the B-operand of the swapped QK^T)
    s16x8 aq[2];
    aq[0] = *(const s16x8*)&base[(size_t)(q0 + lr) * 1536 + h * 64 + lg * 8];
    aq[1] = *(const s16x8*)&base[(size_t)(q0 + lr) * 1536 + h * 64 + 32 + lg * 8];

    f32x4 o[4];
    float m_ = -INFINITY, l_ = 0.f;
    #pragma unroll
    for (int f = 0; f < 4; f++) o[f] = f32x4{0.f, 0.f, 0.f, 0.f};

    const int kt0 = causal ? 0 : qt, kt1 = causal ? qt : 15;

    auto stageK = [&](int bufi, int kt) {
        #pragma unroll
        for (int i = 0; i < 2; i++) {
            const int j = w * 2 + i;
            const int r = j * 8 + (l >> 3);
            const int ck = (l & 7) ^ (r & 7);
            gll16(&base[(size_t)(kt * 64 + r) * 1536 + 512 + h * 64 + ck * 8],
                  &Ks[bufi][j * 512]);
        }
    };
    // V tile: thread covers key row jv = t&63, dims d = w*16 + 0..15
    const int jv = t & 63;
    s16x8 va, vb;
    auto loadV = [&](int kt) {
        const u16* vr = &base[(size_t)(kt * 64 + jv) * 1536 + 1024 + h * 64 + w * 16];
        va = *(const s16x8*)&vr[0];
        vb = *(const s16x8*)&vr[8];
    };
    auto writeV = [&](int bufi) {
        #pragma unroll
        for (int i = 0; i < 8; i++) {
            const int d = w * 16 + i;
            Vs[bufi][d * 64 + (((jv >> 3) ^ (d & 7)) << 3) + (jv & 7)] = (u16)va[i];
        }
        #pragma unroll
        for (int i = 0; i < 8; i++) {
            const int d = w * 16 + 8 + i;
            Vs[bufi][d * 64 + (((jv >> 3) ^ (d & 7)) << 3) + (jv & 7)] = (u16)vb[i];
        }
    };

    stageK(0, kt0);
    loadV(kt0);
    writeV(0);           // compiler inserts vmcnt wait for va/vb
    __syncthreads();     // drains K glls + ds_writes
    int buf = 0;
    for (int kt = kt0; kt <= kt1; kt++) {
        if (kt < kt1) { stageK(buf ^ 1, kt + 1); loadV(kt + 1); }
        // ---- S^T = K Q^T : lane holds keys {f*16+lg*4+r} for query q0+lr ----
        f32x4 s[4];
        #pragma unroll
        for (int f = 0; f < 4; f++) s[f] = f32x4{0.f, 0.f, 0.f, 0.f};
        #pragma unroll
        for (int kk = 0; kk < 2; kk++)
            #pragma unroll
            for (int f = 0; f < 4; f++) {
                const int row = f * 16 + lr;
                const int ch = kk * 4 + lg;
                s16x8 bk = *(const s16x8*)&Ks[buf][row * 64 + ((ch ^ (row & 7)) << 3)];
                s[f] = __builtin_amdgcn_mfma_f32_16x16x32_bf16(bk, aq[kk], s[f], 0, 0, 0);
            }
        // ---- mask on diagonal tile (key = kt*64+f*16+lg*4+r, q = q0+lr) ----
        if (kt == qt) {
            const int q = q0 + lr;
            #pragma unroll
            for (int f = 0; f < 4; f++)
                #pragma unroll
                for (int r = 0; r < 4; r++) {
                    const int key = kt * 64 + f * 16 + lg * 4 + r;
                    if (causal ? (key > q) : (key < q)) s[f][r] = -INFINITY;
                }
        }
        // ---- softmax: lane-local over 16 regs + 2 shfl across the lg group --
        float rm = s[0][0];
        #pragma unroll
        for (int f = 0; f < 4; f++)
            #pragma unroll
            for (int r = 0; r < 4; r++) rm = fmaxf(rm, s[f][r]);
        rm = fmaxf(rm, __shfl_xor(rm, 16));
        rm = fmaxf(rm, __shfl_xor(rm, 32));
        const float mn = fmaxf(m_, rm);
        const float sc = __expf(m_ - mn);
        float ps = 0.f;
        #pragma unroll
        for (int f = 0; f < 4; f++)
            #pragma unroll
            for (int r = 0; r < 4; r++) {
                float p = __expf(s[f][r] - mn);
                s[f][r] = p;
                ps += p;
            }
        ps += __shfl_xor(ps, 16);
        ps += __shfl_xor(ps, 32);
        l_ = l_ * sc + ps;
        m_ = mn;
        // ---- pack P^T pairs to bf16 (lo=key r, hi=key r+1) ----
        u32 P01[4], P23[4];
        #pragma unroll
        for (int f = 0; f < 4; f++) {
            P01[f] = cvtpk(s[f][0], s[f][1]);
            P23[f] = cvtpk(s[f][2], s[f][3]);
        }
        // ---- rescale O (scale for q = lg*4+r fetched from lane lg*4+r) ----
        #pragma unroll
        for (int r = 0; r < 4; r++) {
            const float scr = __shfl(sc, lg * 4 + r);
            #pragma unroll
            for (int f = 0; f < 4; f++) o[f][r] *= scr;
        }
        // ---- O += P V : build A-frag via bpermute, MFMA against Vs ----
        const int srcA = lr + ((lg & 1) << 5);   // lane lr + 16*(2*(lg&1))
        const int srcB = srcA + 16;
        #pragma unroll
        for (int kk = 0; kk < 2; kk++) {
            // candidates f0 = 2kk (lg<2), f1 = 2kk+1 (lg>=2)
            const u32 a01_0 = (u32)__shfl((int)P01[2 * kk], srcA);
            const u32 a01_1 = (u32)__shfl((int)P01[2 * kk + 1], srcA);
            const u32 a23_0 = (u32)__shfl((int)P23[2 * kk], srcA);
            const u32 a23_1 = (u32)__shfl((int)P23[2 * kk + 1], srcA);
            const u32 b01_0 = (u32)__shfl((int)P01[2 * kk], srcB);
            const u32 b01_1 = (u32)__shfl((int)P01[2 * kk + 1], srcB);
            const u32 b23_0 = (u32)__shfl((int)P23[2 * kk], srcB);
            const u32 b23_1 = (u32)__shfl((int)P23[2 * kk + 1], srcB);
            i32x4 av;
            av[0] = (int)((lg & 2) ? a01_1 : a01_0);
            av[1] = (int)((lg & 2) ? a23_1 : a23_0);
            av[2] = (int)((lg & 2) ? b01_1 : b01_0);
            av[3] = (int)((lg & 2) ? b23_1 : b23_0);
            const s16x8 ap = __builtin_bit_cast(s16x8, av);
            #pragma unroll
            for (int f = 0; f < 4; f++) {
                const int row = f * 16 + lr;
                const int ch = kk * 4 + lg;
                s16x8 bv = *(const s16x8*)&Vs[buf][row * 64 + ((ch ^ (row & 7)) << 3)];
                o[f] = __builtin_amdgcn_mfma_f32_16x16x32_bf16(ap, bv, o[f], 0, 0, 0);
            }
        }
        if (kt < kt1) writeV(buf ^ 1);   // before barrier -> visible next iter
        __syncthreads();
        buf ^= 1;
    }
    // ---- epilogue: q = q0 + lg*4 + r, d = f*16 + lr (head-slow merge) ----
    const float linv = 1.f / l_;
    #pragma unroll
    for (int r = 0; r < 4; r++) {
        const float lv = __shfl(linv, lg * 4 + r);
        #pragma unroll
        for (int f = 0; f < 4; f++)
            AO[(size_t)(b * NTOK + q0 + lg * 4 + r) * PL + h * 64 + f * 16 + lr] = o[f][r] * lv;
    }
}

// ---------------------------------------------------------------------------
// add+LN A: x(f32)+attn(f32) -> LN -> hi/lo bf16. z = layer.
// ---------------------------------------------------------------------------
__global__ __launch_bounds__(256) void add_ln_a(const float* __restrict__ X,
    const float* __restrict__ A0, const float* __restrict__ A1,
    const float* __restrict__ g0, const float* __restrict__ g1,
    const float* __restrict__ be0, const float* __restrict__ be1,
    u16* __restrict__ OhiB, u16* __restrict__ OloB, const size_t oLS)
{
    const int z = blockIdx.z;
    const float* A = z ? A1 : A0;
    const float* g = z ? g1 : g0;
    const float* be = z ? be1 : be0;
    u16* Ohi = OhiB + (size_t)z * oLS;
    u16* Olo = OloB + (size_t)z * oLS;
    const int row = blockIdx.x * 4 + (threadIdx.x >> 6);
    const int lane = threadIdx.x & 63;
    const float* xr = X + (size_t)row * PL;
    const float* ar = A + (size_t)row * PL;
    float v[8];
    float sum = 0.f;
    #pragma unroll
    for (int u = 0; u < 8; u++) { v[u] = xr[lane + u * 64] + ar[lane + u * 64]; sum += v[u]; }
    #pragma unroll
    for (int o = 32; o > 0; o >>= 1) sum += __shfl_xor(sum, o);
    const float mu = sum * (1.f / 512.f);
    float s2 = 0.f;
    #pragma unroll
    for (int u = 0; u < 8; u++) { float d = v[u] - mu; s2 = fmaf(d, d, s2); }
    #pragma unroll
    for (int o = 32; o > 0; o >>= 1) s2 += __shfl_xor(s2, o);
    const float rstd = rsqrtf(s2 * (1.f / 512.f) + 1e-5f);
    #pragma unroll
    for (int u = 0; u < 8; u++) {
        const int c = lane + u * 64;
        float y = (v[u] - mu) * rstd * g[c] + be[c];
        u16 hv = f2bf(y);
        Ohi[(size_t)row * PL + c] = hv;
        Olo[(size_t)row * PL + c] = f2bf(y - bf2f(hv));
    }
}

// ---------------------------------------------------------------------------
// add+LN B: (x1 hi+lo) + (ff hi+lo) -> LN -> sigmoid -> bf16 td. z = layer.
// ---------------------------------------------------------------------------
__global__ __launch_bounds__(256) void add_ln_b(
    const u16* __restrict__ XhiB, const u16* __restrict__ XloB, const size_t xLS,
    const u16* __restrict__ F0h, const u16* __restrict__ F1h,
    const u16* __restrict__ F0l, const u16* __restrict__ F1l,
    const float* __restrict__ g0, const float* __restrict__ g1,
    const float* __restrict__ be0, const float* __restrict__ be1,
    u16* __restrict__ TD0, u16* __restrict__ TD1)
{
    const int z = blockIdx.z;
    const u16* Xhi = XhiB + (size_t)z * xLS;
    const u16* Xlo = XloB + (size_t)z * xLS;
    const u16* Fh = z ? F1h : F0h;
    const u16* Fl = z ? F1l : F0l;
    const float* g = z ? g1 : g0;
    const float* be = z ? be1 : be0;
    u16* TD = z ? TD1 : TD0;
    const int row = blockIdx.x * 4 + (threadIdx.x >> 6);
    const int lane = threadIdx.x & 63;
    const size_t ro = (size_t)row * PL;
    float v[8];
    float sum = 0.f;
    #pragma unroll
    for (int u = 0; u < 8; u++) {
        const int c = lane + u * 64;
        v[u] = bf2f(Xhi[ro + c]) + bf2f(Xlo[ro + c]) + bf2f(Fh[ro + c]) + bf2f(Fl[ro + c]);
        sum += v[u];
    }
    #pragma unroll
    for (int o = 32; o > 0; o >>= 1) sum += __shfl_xor(sum, o);
    const float mu = sum * (1.f / 512.f);
    float s2 = 0.f;
    #pragma unroll
    for (int u = 0; u < 8; u++) { float d = v[u] - mu; s2 = fmaf(d, d, s2); }
    #pragma unroll
    for (int o = 32; o > 0; o >>= 1) s2 += __shfl_xor(s2, o);
    const float rstd = rsqrtf(s2 * (1.f / 512.f) + 1e-5f);
    #pragma unroll
    for (int u = 0; u < 8; u++) {
        const int c = lane + u * 64;
        float y = (v[u] - mu) * rstd * g[c] + be[c];
        TD[ro + c] = f2bf(1.f / (1.f + expf(-y)));
    }
}

// ---------------------------------------------------------------------------
// sim: per batch, C[i][j] = dot(td1[i,:], td2[j,:]) / 512  (plain bf16 MFMA)
// gll-staged, BK=64, dbuf (R8 form).
// ---------------------------------------------------------------------------
__global__ __launch_bounds__(256) void sim_mfma(const u16* __restrict__ TD1,
    const u16* __restrict__ TD2, float* __restrict__ Out)
{
    __shared__ u16 Ah[2][128 * 64], Bh[2][128 * 64];
    const int t = threadIdx.x, l = t & 63, w = t >> 6;
    const int lr = l & 15, lg = l >> 4;
    const int wm = w >> 1, wn = w & 1;
    const int bz = blockIdx.z;
    const u16* A = TD1 + (size_t)bz * NTOK * PL;
    const u16* B = TD2 + (size_t)bz * NTOK * PL;
    const int m0 = blockIdx.x * 128, n0 = blockIdx.y * 128;

    f32x4 acc[4][4];
    #pragma unroll
    for (int i = 0; i < 4; i++)
        #pragma unroll
        for (int j = 0; j < 4; j++) acc[i][j] = f32x4{0.f, 0.f, 0.f, 0.f};

    auto stage = [&](int bufi, int k0) {
        #pragma unroll
        for (int i = 0; i < 4; i++) {
            const int j = w * 4 + i;
            const int r = j * 8 + (l >> 3);
            const int ck = (l & 7) ^ (r & 7);
            gll16(&A[(size_t)(m0 + r) * 512 + k0 + ck * 8], &Ah[bufi][j * 512]);
            gll16(&B[(size_t)(n0 + r) * 512 + k0 + ck * 8], &Bh[bufi][j * 512]);
        }
    };

    stage(0, 0);
    __syncthreads();
    int buf = 0;
    for (int kt = 0; kt < 8; kt++) {
        if (kt < 7) stage(buf ^ 1, (kt + 1) * 64);
        #pragma unroll
        for (int kk = 0; kk < 2; kk++) {
            const int ch = kk * 4 + lg;
            s16x8 af[4], bf[4];
            #pragma unroll
            for (int fm = 0; fm < 4; fm++) {
                const int r = wm * 64 + fm * 16 + lr;
                af[fm] = *(const s16x8*)&Ah[buf][r * 64 + ((ch ^ (r & 7)) << 3)];
            }
            #pragma unroll
            for (int fn = 0; fn < 4; fn++) {
                const int r = wn * 64 + fn * 16 + lr;
                bf[fn] = *(const s16x8*)&Bh[buf][r * 64 + ((ch ^ (r & 7)) << 3)];
            }
            #pragma unroll
            for (int fm = 0; fm < 4; fm++)
                #pragma unroll
                for (int fn = 0; fn < 4; fn++)
                    acc[fm][fn] = __builtin_amdgcn_mfma_f32_16x16x32_bf16(af[fm], bf[fn], acc[fm][fn], 0, 0, 0);
        }
        __syncthreads();
        buf ^= 1;
    }
    #pragma unroll
    for (int fm = 0; fm < 4; fm++)
        #pragma unroll
        for (int fn = 0; fn < 4; fn++)
            #pragma unroll
            for (int rg = 0; rg < 4; rg++) {
                const int r = m0 + wm * 64 + fm * 16 + lg * 4 + rg;
                const int c = n0 + wn * 64 + fn * 16 + lr;
                Out[((size_t)(bz * NTOK + r)) * NTOK + c] = acc[fm][fn][rg] * (1.f / 512.f);
            }
}

// ---------------------------------------------------------------------------
extern "C" void kernel_launch(void* const* d_in, const int* in_sizes, int n_in,
                              void* d_out, int out_size, void* d_ws, size_t ws_size,
                              hipStream_t stream)
{
    const float* x = (const float*)d_in[0];
    const float* wqkv[2] = {(const float*)d_in[1],  (const float*)d_in[11]};
    const float* bqkv[2] = {(const float*)d_in[2],  (const float*)d_in[12]};
    const float* ga[2]   = {(const float*)d_in[3],  (const float*)d_in[13]};
    const float* bea[2]  = {(const float*)d_in[4],  (const float*)d_in[14]};
    const float* w1[2]   = {(const float*)d_in[5],  (const float*)d_in[15]};
    const float* b1[2]   = {(const float*)d_in[6],  (const float*)d_in[16]};
    const float* w2[2]   = {(const float*)d_in[7],  (const float*)d_in[17]};
    const float* b2[2]   = {(const float*)d_in[8],  (const float*)d_in[18]};
    const float* gb[2]   = {(const float*)d_in[9],  (const float*)d_in[19]};
    const float* beb[2]  = {(const float*)d_in[10], (const float*)d_in[20]};

    // -------- workspace map (KB offsets; identical to R10's proven layout) --
    char* wsb = (char*)d_ws;
    char* ob  = (char*)d_out;
    #define WSK(kb) ((char*)wsb + ((size_t)(kb) << 10))
    #define OBK(kb) ((char*)ob  + ((size_t)(kb) << 10))
    // ws [0,8M):  xhi/xlo (S0-S2)  -> x1h z0/z1 (S4-S7)
    u16* xhi = (u16*)WSK(0);
    u16* xlo = (u16*)WSK(4096);
    u16* x1h = (u16*)WSK(0);          // + z*2097152 elems
    // ws [8,11M): wqh (S1-S2) -> td1 ws[8,12) (S7-)
    u16* wqh = (u16*)WSK(8192);       // + z*786432 elems
    u16* td1 = (u16*)WSK(8192);
    // ws [11,13M): w1h, w2h (S1-S6); td2 ws[12,16) (S7-)
    u16* w1h = (u16*)WSK(11264);      // + z*262144 elems
    u16* w2h = (u16*)WSK(12288);      // + z*262144 elems
    u16* td2 = (u16*)WSK(12288);
    // ws [13,37M): qkvB (S2-S3)
    u16* qkvB = (u16*)WSK(13312);     // [z][4096][1536]
    // ws [16,24M): x1l z0/z1 (S4-S7)
    u16* x1l = (u16*)WSK(16384);      // + z*2097152 elems
    // ws [24,40M): ffo hi/lo (S6-S7)
    u16* ffo0h = (u16*)WSK(24576);
    u16* ffo0l = (u16*)WSK(28672);
    u16* ffo1h = (u16*)WSK(32768);
    u16* ffo1l = (u16*)WSK(36864);
    // d_out: AO0/AO1 f32 (S3-S4); h hi/lo (S5-S6); final out (S8)
    float* AO0 = (float*)OBK(0);
    float* AO1 = (float*)OBK(8192);
    u16* h0h = (u16*)OBK(0);
    u16* h0l = (u16*)OBK(4096);
    u16* h1h = (u16*)OBK(8192);
    u16* h1l = (u16*)OBK(12288);
    float* out = (float*)d_out;

    // S0: x split
    convert_x<<<2048, 256, 0, stream>>>(x, xhi, xlo);
    // S1: weight transposes (hi only)
    convert_wt<<<dim3(16, 48, 2), 256, 0, stream>>>(wqkv[0], wqkv[1], wqh, 786432, 1536);
    convert_wt<<<dim3(16, 16, 2), 256, 0, stream>>>(w1[0], w1[1], w1h, 262144, 512);
    convert_wt<<<dim3(16, 16, 2), 256, 0, stream>>>(w2[0], w2[1], w2h, 262144, 512);
    // S2: qkv gemm — permuted-B, linear output into qkvB
    gemm_split<128, 0><<<dim3(32, 12, 2), 256, 0, stream>>>(
        xhi, xlo, 0, wqh, 786432, bqkv[0], bqkv[1], 1536,
        qkvB, qkvB, nullptr, nullptr);
    // S3: attention (z=0 causal, z=1 anti-causal)
    attn_mfma<<<dim3(32, 16, 2), 256, 0, stream>>>(qkvB, AO0, AO1);
    // S4: add + LN -> x1 hi/lo
    add_ln_a<<<dim3(1024, 1, 2), 256, 0, stream>>>(x, AO0, AO1,
        ga[0], ga[1], bea[0], bea[1], x1h, x1l, 2097152);
    // S5: ff1 (gelu) -> h hi/lo (in d_out)
    gemm_split<64, 1><<<dim3(64, 4, 2), 256, 0, stream>>>(
        x1h, x1l, 2097152, w1h, 262144, b1[0], b1[1], 512,
        h0h, h1h, h0l, h1l);
    // S6: ff2 -> ffo hi/lo (in ws)
    gemm_split<64, 2><<<dim3(64, 4, 2), 256, 0, stream>>>(
        h0h, h0l, 2097152, w2h, 262144, b2[0], b2[1], 512,
        ffo0h, ffo1h, ffo0l, ffo1l);
    // S7: add + LN + sigmoid -> td
    add_ln_b<<<dim3(1024, 1, 2), 256, 0, stream>>>(
        x1h, x1l, 2097152, ffo0h, ffo1h, ffo0l, ffo1l,
        gb[0], gb[1], beb[0], beb[1], td1, td2);
    // S8: sim
    sim_mfma<<<dim3(8, 8, 4), 256, 0, stream>>>(td1, td2, out);
}

// Round 12
// 160.620 us; speedup vs baseline: 1.1309x; 1.0094x over previous
//
#include <hip/hip_runtime.h>
#include <math.h>

// ---------------------------------------------------------------------------
// bf16-MFMA implementation, both layers merged (z=2), global_load_lds staging.
//  - all dense GEMMs: 2-term split (A hi/lo × B hi) — R7/R8-proven numerics
//  - R10: qkv linear [z][4096][1536] output via permuted weight rows
//  - R11: attention swapped-QK^T, in-register P (cvt_pk + shfl redistribute)
//  - R12: attn att[2] pipeline (QK(t+1) -> PV(t) -> SM(t+1)), setprio around
//    MFMA cluster, defer-max rescale skip. Only attn_mfma changed vs R11.
// ---------------------------------------------------------------------------

typedef float f32x4 __attribute__((ext_vector_type(4)));
typedef short s16x8 __attribute__((ext_vector_type(8)));
typedef int   i32x4 __attribute__((ext_vector_type(4)));
typedef unsigned short u16;
typedef unsigned int u32;

#define NTOK 1024
#define PL 512
#define QSCALE 0.04419417382415922f  // 1/sqrt(512)

__device__ inline u16 f2bf(float f) {
    unsigned u = __builtin_bit_cast(unsigned, f);
    unsigned r = u + 0x7fffu + ((u >> 16) & 1u);   // RNE
    return (u16)(r >> 16);
}
__device__ inline float bf2f(u16 h) {
    unsigned u = ((unsigned)h) << 16;
    return __builtin_bit_cast(float, u);
}
__device__ inline u32 cvtpk(float a, float b) {   // lo=a, hi=b (RNE)
    u32 r;
    asm("v_cvt_pk_bf16_f32 %0, %1, %2" : "=v"(r) : "v"(a), "v"(b));
    return r;
}

__device__ inline void gll16(const void* g, void* l) {
    __builtin_amdgcn_global_load_lds(
        (const __attribute__((address_space(1))) u32*)g,
        (__attribute__((address_space(3))) u32*)l, 16, 0, 0);
}

// ---------------------------------------------------------------------------
// x -> hi/lo bf16 split (elementwise)
// ---------------------------------------------------------------------------
__global__ __launch_bounds__(256) void convert_x(const float* __restrict__ X,
    u16* __restrict__ hi, u16* __restrict__ lo)
{
    const int i = (blockIdx.x * 256 + threadIdx.x) * 4;
    float4 v = *(const float4*)&X[i];
    float vv[4] = {v.x, v.y, v.z, v.w};
    #pragma unroll
    for (int j = 0; j < 4; j++) {
        u16 h = f2bf(vv[j]);
        hi[i + j] = h;
        lo[i + j] = f2bf(vv[j] - bf2f(h));
    }
}

// ---------------------------------------------------------------------------
// W [512][N] f32 -> Wt [N][512] bf16 hi (tiled transpose), z = layer
// ---------------------------------------------------------------------------
__global__ __launch_bounds__(256) void convert_wt(const float* __restrict__ W0,
    const float* __restrict__ W1, u16* __restrict__ WhiB, const size_t dLS, const int N)
{
    const float* W = blockIdx.z ? W1 : W0;
    u16* Whi = WhiB + (size_t)blockIdx.z * dLS;
    __shared__ float T[32][36];
    const int k0 = blockIdx.x * 32, n0 = blockIdx.y * 32;
    const int tr = threadIdx.x >> 3, tc = (threadIdx.x & 7) * 4;
    *(float4*)&T[tr][tc] = *(const float4*)&W[(size_t)(k0 + tr) * N + n0 + tc];
    __syncthreads();
    const size_t o = (size_t)(n0 + tr) * 512 + k0 + tc;
    #pragma unroll
    for (int j = 0; j < 4; j++) Whi[o + j] = f2bf(T[tc + j][tr]);
}

// π: permuted col j -> original col (head-fast split c2 = dd*8+h)
__device__ inline int qkv_perm(int j) {
    return (j >> 9) * 512 + ((j & 63) << 3) + ((j >> 6) & 7);
}

// ---------------------------------------------------------------------------
// 2-term split-bf16 MFMA GEMM, z = layer. A[4096][512] (hi/lo) x Bt[N][512] (hi).
// EPI: 0 = qkv (B rows permuted, linear [z*4096+r][1536] output, Q scaled),
//      1 = gelu -> hi/lo, 2 = plain hi/lo.
// BK=32; dbuf gll staging (stage kt+1 before compute kt, 1 barrier).
// ---------------------------------------------------------------------------
template<int BM, int EPI>
__global__ __launch_bounds__(256) void gemm_split(
    const u16* __restrict__ AhiB, const u16* __restrict__ AloB, const size_t aLS,
    const u16* __restrict__ BhiB, const size_t bLS,
    const float* __restrict__ bias0, const float* __restrict__ bias1, const int Ncols,
    u16* __restrict__ oh0, u16* __restrict__ oh1,
    u16* __restrict__ ol0, u16* __restrict__ ol1)
{
    constexpr int FM = BM / 32;
    __shared__ u16 Ah[2][BM * 32], Al[2][BM * 32], Bh[2][128 * 32];
    const int z = blockIdx.z;
    const u16* Ahi = AhiB + (size_t)z * aLS;
    const u16* Alo = AloB + (size_t)z * aLS;
    const u16* Bhi = BhiB + (size_t)z * bLS;
    const float* bias = z ? bias1 : bias0;
    u16* oh = z ? oh1 : oh0;
    u16* ol = z ? ol1 : ol0;

    const int t = threadIdx.x, l = t & 63, w = t >> 6;
    const int lr = l & 15, lg = l >> 4;
    const int wm = w >> 1, wn = w & 1;
    const int m0 = blockIdx.x * BM, n0 = blockIdx.y * 128;
    const int srow = l >> 2, sch = l & 3;    // staging lane coords (16 rows/KB)

    f32x4 acc[FM][4];
    #pragma unroll
    for (int i = 0; i < FM; i++)
        #pragma unroll
        for (int j = 0; j < 4; j++) acc[i][j] = f32x4{0.f, 0.f, 0.f, 0.f};

    auto stage = [&](int bufi, int k0) {
        #pragma unroll
        for (int i = 0; i < BM / 64; i++) {
            const int j = w * (BM / 64) + i;
            const int r = j * 16 + srow;
            const int ck = sch ^ ((r >> 1) & 3);
            const size_t g = (size_t)(m0 + r) * 512 + k0 + ck * 8;
            gll16(&Ahi[g], &Ah[bufi][j * 512]);
            gll16(&Alo[g], &Al[bufi][j * 512]);
        }
        #pragma unroll
        for (int i = 0; i < 2; i++) {
            const int j = w * 2 + i;
            const int r = j * 16 + srow;
            const int ck = sch ^ ((r >> 1) & 3);
            const int brow = (EPI == 0) ? qkv_perm(n0 + r) : (n0 + r);
            gll16(&Bhi[(size_t)brow * 512 + k0 + ck * 8], &Bh[bufi][j * 512]);
        }
    };

    stage(0, 0);
    __syncthreads();
    int buf = 0;
    for (int kt = 0; kt < 16; kt++) {
        if (kt < 15) stage(buf ^ 1, (kt + 1) * 32);

        s16x8 ah[FM], al[FM];
        #pragma unroll
        for (int fm = 0; fm < FM; fm++) {
            const int r = wm * (BM / 2) + fm * 16 + lr;
            const int d = r * 32 + ((lg ^ ((r >> 1) & 3)) << 3);
            ah[fm] = *(const s16x8*)&Ah[buf][d];
            al[fm] = *(const s16x8*)&Al[buf][d];
        }
        #pragma unroll
        for (int fn = 0; fn < 4; fn++) {
            const int r = wn * 64 + fn * 16 + lr;
            const int d = r * 32 + ((lg ^ ((r >> 1) & 3)) << 3);
            s16x8 bh = *(const s16x8*)&Bh[buf][d];
            #pragma unroll
            for (int fm = 0; fm < FM; fm++) {
                acc[fm][fn] = __builtin_amdgcn_mfma_f32_16x16x32_bf16(ah[fm], bh, acc[fm][fn], 0, 0, 0);
                acc[fm][fn] = __builtin_amdgcn_mfma_f32_16x16x32_bf16(al[fm], bh, acc[fm][fn], 0, 0, 0);
            }
        }
        __syncthreads();   // waves done with buf; stage(buf^1) drained
        buf ^= 1;
    }
    // epilogue
    #pragma unroll
    for (int fm = 0; fm < FM; fm++)
        #pragma unroll
        for (int fn = 0; fn < 4; fn++)
            #pragma unroll
            for (int rg = 0; rg < 4; rg++) {
                const int r = m0 + wm * (BM / 2) + fm * 16 + lg * 4 + rg;
                const int c = n0 + wn * 64 + fn * 16 + lr;
                if constexpr (EPI == 0) {
                    float v = acc[fm][fn][rg] + bias[qkv_perm(c)];
                    if (c < 512) v *= QSCALE;   // Q third (uniform per block)
                    oh[((size_t)z * 4096 + r) * Ncols + c] = f2bf(v);
                } else {
                    float gl = acc[fm][fn][rg] + bias[c];
                    if constexpr (EPI == 1)
                        gl = 0.5f * gl * (1.f + erff(gl * 0.70710678118654752f));
                    u16 hv = f2bf(gl);
                    oh[(size_t)r * Ncols + c] = hv;
                    ol[(size_t)r * Ncols + c] = f2bf(gl - bf2f(hv));
                }
            }
}

// ---------------------------------------------------------------------------
// Flash attention, bf16 MFMA, z = layer (z==0 causal, z==1 anti-causal).
// R12: att[2] pipeline — per iter: QK(t+1) -> PV(t, pending P) -> SM(t+1).
// Swapped QK^T, lane-local softmax, in-register P; defer-max rescale skip;
// setprio(1) around the MFMA cluster. K ring 2-deep by kt&1; V reg->LDS.
// ---------------------------------------------------------------------------
__global__ __launch_bounds__(256) void attn_mfma(const u16* __restrict__ QKV,
    float* __restrict__ AO0, float* __restrict__ AO1)
{
    __shared__ u16 Ks[2][64 * 64];
    __shared__ u16 Vs[2][64 * 64];
    const int t = threadIdx.x, l = t & 63, w = t >> 6;
    const int lr = l & 15, lg = l >> 4;
    const int z = blockIdx.z;
    const int causal = (z == 0);
    const int bh = blockIdx.x;
    const int b = bh >> 3, h = bh & 7;
    const int qt = causal ? (15 - (int)blockIdx.y) : (int)blockIdx.y;  // long jobs first
    const u16* base = QKV + ((size_t)z * 4096 + (size_t)b * NTOK) * 1536;
    float* AO = z ? AO1 : AO0;
    const int q0 = qt * 64 + w * 16;

    // Q fragments (B-operand of the swapped QK^T)
    s16x8 aq[2];
    aq[0] = *(const s16x8*)&base[(size_t)(q0 + lr) * 1536 + h * 64 + lg * 8];
    aq[1] = *(const s16x8*)&base[(size_t)(q0 + lr) * 1536 + h * 64 + 32 + lg * 8];

    f32x4 o[4];
    float m_ = -INFINITY, l_ = 0.f;
    #pragma unroll
    for (int f = 0; f < 4; f++) o[f] = f32x4{0.f, 0.f, 0.f, 0.f};

    const int kt0 = causal ? 0 : qt, kt1 = causal ? qt : 15;

    auto stageK = [&](int kt) {
        #pragma unroll
        for (int i = 0; i < 2; i++) {
            const int j = w * 2 + i;
            const int r = j * 8 + (l >> 3);
            const int ck = (l & 7) ^ (r & 7);
            gll16(&base[(size_t)(kt * 64 + r) * 1536 + 512 + h * 64 + ck * 8],
                  &Ks[kt & 1][j * 512]);
        }
    };
    const int jv = t & 63;
    s16x8 va, vb;
    auto loadV = [&](int kt) {
        const u16* vr = &base[(size_t)(kt * 64 + jv) * 1536 + 1024 + h * 64 + w * 16];
        va = *(const s16x8*)&vr[0];
        vb = *(const s16x8*)&vr[8];
    };
    auto writeV = [&](int kt) {
        #pragma unroll
        for (int i = 0; i < 8; i++) {
            const int d = w * 16 + i;
            Vs[kt & 1][d * 64 + (((jv >> 3) ^ (d & 7)) << 3) + (jv & 7)] = (u16)va[i];
        }
        #pragma unroll
        for (int i = 0; i < 8; i++) {
            const int d = w * 16 + 8 + i;
            Vs[kt & 1][d * 64 + (((jv >> 3) ^ (d & 7)) << 3) + (jv & 7)] = (u16)vb[i];
        }
    };

    // pending P-state (tile t), consumed by PV(t) one iteration later
    s16x8 pap[2];
    float psc[4] = {1.f, 1.f, 1.f, 1.f};
    int pneed = 1;

    auto QK = [&](int kt, f32x4* s) {
        #pragma unroll
        for (int f = 0; f < 4; f++) s[f] = f32x4{0.f, 0.f, 0.f, 0.f};
        #pragma unroll
        for (int kk = 0; kk < 2; kk++)
            #pragma unroll
            for (int f = 0; f < 4; f++) {
                const int row = f * 16 + lr;
                const int ch = kk * 4 + lg;
                s16x8 bk = *(const s16x8*)&Ks[kt & 1][row * 64 + ((ch ^ (row & 7)) << 3)];
                s[f] = __builtin_amdgcn_mfma_f32_16x16x32_bf16(bk, aq[kk], s[f], 0, 0, 0);
            }
        if (kt == qt) {
            const int q = q0 + lr;
            #pragma unroll
            for (int f = 0; f < 4; f++)
                #pragma unroll
                for (int r = 0; r < 4; r++) {
                    const int key = kt * 64 + f * 16 + lg * 4 + r;
                    if (causal ? (key > q) : (key < q)) s[f][r] = -INFINITY;
                }
        }
    };

    auto SM = [&](f32x4* s) {
        float rm = s[0][0];
        #pragma unroll
        for (int f = 0; f < 4; f++)
            #pragma unroll
            for (int r = 0; r < 4; r++) rm = fmaxf(rm, s[f][r]);
        rm = fmaxf(rm, __shfl_xor(rm, 16));
        rm = fmaxf(rm, __shfl_xor(rm, 32));
        pneed = !__all(rm <= m_ + 8.f);          // defer-max (T13)
        const float mn = pneed ? fmaxf(m_, rm) : m_;
        const float sc = __expf(m_ - mn);        // ==1 when deferred
        float ps = 0.f;
        #pragma unroll
        for (int f = 0; f < 4; f++)
            #pragma unroll
            for (int r = 0; r < 4; r++) {
                float p = __expf(s[f][r] - mn);
                s[f][r] = p;
                ps += p;
            }
        ps += __shfl_xor(ps, 16);
        ps += __shfl_xor(ps, 32);
        l_ = l_ * sc + ps;
        m_ = mn;
        // pack P^T pairs + redistribute to PV A-frags
        u32 P01[4], P23[4];
        #pragma unroll
        for (int f = 0; f < 4; f++) {
            P01[f] = cvtpk(s[f][0], s[f][1]);
            P23[f] = cvtpk(s[f][2], s[f][3]);
        }
        const int srcA = lr + ((lg & 1) << 5);
        const int srcB = srcA + 16;
        #pragma unroll
        for (int kk = 0; kk < 2; kk++) {
            const u32 a01_0 = (u32)__shfl((int)P01[2 * kk], srcA);
            const u32 a01_1 = (u32)__shfl((int)P01[2 * kk + 1], srcA);
            const u32 a23_0 = (u32)__shfl((int)P23[2 * kk], srcA);
            const u32 a23_1 = (u32)__shfl((int)P23[2 * kk + 1], srcA);
            const u32 b01_0 = (u32)__shfl((int)P01[2 * kk], srcB);
            const u32 b01_1 = (u32)__shfl((int)P01[2 * kk + 1], srcB);
            const u32 b23_0 = (u32)__shfl((int)P23[2 * kk], srcB);
            const u32 b23_1 = (u32)__shfl((int)P23[2 * kk + 1], srcB);
            i32x4 av;
            av[0] = (int)((lg & 2) ? a01_1 : a01_0);
            av[1] = (int)((lg & 2) ? a23_1 : a23_0);
            av[2] = (int)((lg & 2) ? b01_1 : b01_0);
            av[3] = (int)((lg & 2) ? b23_1 : b23_0);
            pap[kk] = __builtin_bit_cast(s16x8, av);
        }
        if (pneed) {
            #pragma unroll
            for (int r = 0; r < 4; r++) psc[r] = __shfl(sc, lg * 4 + r);
        }
    };

    auto PV = [&](int kt) {
        if (pneed) {
            #pragma unroll
            for (int r = 0; r < 4; r++)
                #pragma unroll
                for (int f = 0; f < 4; f++) o[f][r] *= psc[r];
        }
        #pragma unroll
        for (int kk = 0; kk < 2; kk++)
            #pragma unroll
            for (int f = 0; f < 4; f++) {
                const int row = f * 16 + lr;
                const int ch = kk * 4 + lg;
                s16x8 bv = *(const s16x8*)&Vs[kt & 1][row * 64 + ((ch ^ (row & 7)) << 3)];
                o[f] = __builtin_amdgcn_mfma_f32_16x16x32_bf16(pap[kk], bv, o[f], 0, 0, 0);
            }
    };

    // ---- prologue: stage K(kt0[,kt0+1]) + V(kt0); QK+SM of tile kt0 ----
    stageK(kt0);
    if (kt0 < kt1) stageK(kt0 + 1);
    loadV(kt0);
    writeV(kt0);          // compiler waits vmcnt for va/vb
    __syncthreads();      // K glls + V ds_writes visible
    {
        f32x4 s0[4];
        QK(kt0, s0);
        SM(s0);
    }
    __syncthreads();      // all waves done reading Ks[kt0&1] before stageK(kt0+2)

    // ---- main loop: QK(t+1) -> PV(t) -> SM(t+1) ----
    for (int kt = kt0; kt <= kt1; kt++) {
        if (kt + 2 <= kt1) stageK(kt + 2);
        if (kt + 1 <= kt1) loadV(kt + 1);
        f32x4 sn[4];
        __builtin_amdgcn_s_setprio(1);
        if (kt + 1 <= kt1) QK(kt + 1, sn);
        PV(kt);
        __builtin_amdgcn_s_setprio(0);
        if (kt + 1 <= kt1) {
            SM(sn);
            writeV(kt + 1);
        }
        __syncthreads();
    }

    // ---- epilogue: q = q0 + lg*4 + r, d = f*16 + lr (head-slow merge) ----
    const float linv = 1.f / l_;
    #pragma unroll
    for (int r = 0; r < 4; r++) {
        const float lv = __shfl(linv, lg * 4 + r);
        #pragma unroll
        for (int f = 0; f < 4; f++)
            AO[(size_t)(b * NTOK + q0 + lg * 4 + r) * PL + h * 64 + f * 16 + lr] = o[f][r] * lv;
    }
}

// ---------------------------------------------------------------------------
// add+LN A: x(f32)+attn(f32) -> LN -> hi/lo bf16. z = layer.
// ---------------------------------------------------------------------------
__global__ __launch_bounds__(256) void add_ln_a(const float* __restrict__ X,
    const float* __restrict__ A0, const float* __restrict__ A1,
    const float* __restrict__ g0, const float* __restrict__ g1,
    const float* __restrict__ be0, const float* __restrict__ be1,
    u16* __restrict__ OhiB, u16* __restrict__ OloB, const size_t oLS)
{
    const int z = blockIdx.z;
    const float* A = z ? A1 : A0;
    const float* g = z ? g1 : g0;
    const float* be = z ? be1 : be0;
    u16* Ohi = OhiB + (size_t)z * oLS;
    u16* Olo = OloB + (size_t)z * oLS;
    const int row = blockIdx.x * 4 + (threadIdx.x >> 6);
    const int lane = threadIdx.x & 63;
    const float* xr = X + (size_t)row * PL;
    const float* ar = A + (size_t)row * PL;
    float v[8];
    float sum = 0.f;
    #pragma unroll
    for (int u = 0; u < 8; u++) { v[u] = xr[lane + u * 64] + ar[lane + u * 64]; sum += v[u]; }
    #pragma unroll
    for (int o = 32; o > 0; o >>= 1) sum += __shfl_xor(sum, o);
    const float mu = sum * (1.f / 512.f);
    float s2 = 0.f;
    #pragma unroll
    for (int u = 0; u < 8; u++) { float d = v[u] - mu; s2 = fmaf(d, d, s2); }
    #pragma unroll
    for (int o = 32; o > 0; o >>= 1) s2 += __shfl_xor(s2, o);
    const float rstd = rsqrtf(s2 * (1.f / 512.f) + 1e-5f);
    #pragma unroll
    for (int u = 0; u < 8; u++) {
        const int c = lane + u * 64;
        float y = (v[u] - mu) * rstd * g[c] + be[c];
        u16 hv = f2bf(y);
        Ohi[(size_t)row * PL + c] = hv;
        Olo[(size_t)row * PL + c] = f2bf(y - bf2f(hv));
    }
}

// ---------------------------------------------------------------------------
// add+LN B: (x1 hi+lo) + (ff hi+lo) -> LN -> sigmoid -> bf16 td. z = layer.
// ---------------------------------------------------------------------------
__global__ __launch_bounds__(256) void add_ln_b(
    const u16* __restrict__ XhiB, const u16* __restrict__ XloB, const size_t xLS,
    const u16* __restrict__ F0h, const u16* __restrict__ F1h,
    const u16* __restrict__ F0l, const u16* __restrict__ F1l,
    const float* __restrict__ g0, const float* __restrict__ g1,
    const float* __restrict__ be0, const float* __restrict__ be1,
    u16* __restrict__ TD0, u16* __restrict__ TD1)
{
    const int z = blockIdx.z;
    const u16* Xhi = XhiB + (size_t)z * xLS;
    const u16* Xlo = XloB + (size_t)z * xLS;
    const u16* Fh = z ? F1h : F0h;
    const u16* Fl = z ? F1l : F0l;
    const float* g = z ? g1 : g0;
    const float* be = z ? be1 : be0;
    u16* TD = z ? TD1 : TD0;
    const int row = blockIdx.x * 4 + (threadIdx.x >> 6);
    const int lane = threadIdx.x & 63;
    const size_t ro = (size_t)row * PL;
    float v[8];
    float sum = 0.f;
    #pragma unroll
    for (int u = 0; u < 8; u++) {
        const int c = lane + u * 64;
        v[u] = bf2f(Xhi[ro + c]) + bf2f(Xlo[ro + c]) + bf2f(Fh[ro + c]) + bf2f(Fl[ro + c]);
        sum += v[u];
    }
    #pragma unroll
    for (int o = 32; o > 0; o >>= 1) sum += __shfl_xor(sum, o);
    const float mu = sum * (1.f / 512.f);
    float s2 = 0.f;
    #pragma unroll
    for (int u = 0; u < 8; u++) { float d = v[u] - mu; s2 = fmaf(d, d, s2); }
    #pragma unroll
    for (int o = 32; o > 0; o >>= 1) s2 += __shfl_xor(s2, o);
    const float rstd = rsqrtf(s2 * (1.f / 512.f) + 1e-5f);
    #pragma unroll
    for (int u = 0; u < 8; u++) {
        const int c = lane + u * 64;
        float y = (v[u] - mu) * rstd * g[c] + be[c];
        TD[ro + c] = f2bf(1.f / (1.f + expf(-y)));
    }
}

// ---------------------------------------------------------------------------
// sim: per batch, C[i][j] = dot(td1[i,:], td2[j,:]) / 512  (plain bf16 MFMA)
// gll-staged, BK=64, dbuf (R8 form).
// ---------------------------------------------------------------------------
__global__ __launch_bounds__(256) void sim_mfma(const u16* __restrict__ TD1,
    const u16* __restrict__ TD2, float* __restrict__ Out)
{
    __shared__ u16 Ah[2][128 * 64], Bh[2][128 * 64];
    const int t = threadIdx.x, l = t & 63, w = t >> 6;
    const int lr = l & 15, lg = l >> 4;
    const int wm = w >> 1, wn = w & 1;
    const int bz = blockIdx.z;
    const u16* A = TD1 + (size_t)bz * NTOK * PL;
    const u16* B = TD2 + (size_t)bz * NTOK * PL;
    const int m0 = blockIdx.x * 128, n0 = blockIdx.y * 128;

    f32x4 acc[4][4];
    #pragma unroll
    for (int i = 0; i < 4; i++)
        #pragma unroll
        for (int j = 0; j < 4; j++) acc[i][j] = f32x4{0.f, 0.f, 0.f, 0.f};

    auto stage = [&](int bufi, int k0) {
        #pragma unroll
        for (int i = 0; i < 4; i++) {
            const int j = w * 4 + i;
            const int r = j * 8 + (l >> 3);
            const int ck = (l & 7) ^ (r & 7);
            gll16(&A[(size_t)(m0 + r) * 512 + k0 + ck * 8], &Ah[bufi][j * 512]);
            gll16(&B[(size_t)(n0 + r) * 512 + k0 + ck * 8], &Bh[bufi][j * 512]);
        }
    };

    stage(0, 0);
    __syncthreads();
    int buf = 0;
    for (int kt = 0; kt < 8; kt++) {
        if (kt < 7) stage(buf ^ 1, (kt + 1) * 64);
        #pragma unroll
        for (int kk = 0; kk < 2; kk++) {
            const int ch = kk * 4 + lg;
            s16x8 af[4], bf[4];
            #pragma unroll
            for (int fm = 0; fm < 4; fm++) {
                const int r = wm * 64 + fm * 16 + lr;
                af[fm] = *(const s16x8*)&Ah[buf][r * 64 + ((ch ^ (r & 7)) << 3)];
            }
            #pragma unroll
            for (int fn = 0; fn < 4; fn++) {
                const int r = wn * 64 + fn * 16 + lr;
                bf[fn] = *(const s16x8*)&Bh[buf][r * 64 + ((ch ^ (r & 7)) << 3)];
            }
            #pragma unroll
            for (int fm = 0; fm < 4; fm++)
                #pragma unroll
                for (int fn = 0; fn < 4; fn++)
                    acc[fm][fn] = __builtin_amdgcn_mfma_f32_16x16x32_bf16(af[fm], bf[fn], acc[fm][fn], 0, 0, 0);
        }
        __syncthreads();
        buf ^= 1;
    }
    #pragma unroll
    for (int fm = 0; fm < 4; fm++)
        #pragma unroll
        for (int fn = 0; fn < 4; fn++)
            #pragma unroll
            for (int rg = 0; rg < 4; rg++) {
                const int r = m0 + wm * 64 + fm * 16 + lg * 4 + rg;
                const int c = n0 + wn * 64 + fn * 16 + lr;
                Out[((size_t)(bz * NTOK + r)) * NTOK + c] = acc[fm][fn][rg] * (1.f / 512.f);
            }
}

// ---------------------------------------------------------------------------
extern "C" void kernel_launch(void* const* d_in, const int* in_sizes, int n_in,
                              void* d_out, int out_size, void* d_ws, size_t ws_size,
                              hipStream_t stream)
{
    const float* x = (const float*)d_in[0];
    const float* wqkv[2] = {(const float*)d_in[1],  (const float*)d_in[11]};
    const float* bqkv[2] = {(const float*)d_in[2],  (const float*)d_in[12]};
    const float* ga[2]   = {(const float*)d_in[3],  (const float*)d_in[13]};
    const float* bea[2]  = {(const float*)d_in[4],  (const float*)d_in[14]};
    const float* w1[2]   = {(const float*)d_in[5],  (const float*)d_in[15]};
    const float* b1[2]   = {(const float*)d_in[6],  (const float*)d_in[16]};
    const float* w2[2]   = {(const float*)d_in[7],  (const float*)d_in[17]};
    const float* b2[2]   = {(const float*)d_in[8],  (const float*)d_in[18]};
    const float* gb[2]   = {(const float*)d_in[9],  (const float*)d_in[19]};
    const float* beb[2]  = {(const float*)d_in[10], (const float*)d_in[20]};

    // -------- workspace map (KB offsets; identical to R10/R11 layout) --
    char* wsb = (char*)d_ws;
    char* ob  = (char*)d_out;
    #define WSK(kb) ((char*)wsb + ((size_t)(kb) << 10))
    #define OBK(kb) ((char*)ob  + ((size_t)(kb) << 10))
    // ws [0,8M):  xhi/xlo (S0-S2)  -> x1h z0/z1 (S4-S7)
    u16* xhi = (u16*)WSK(0);
    u16* xlo = (u16*)WSK(4096);
    u16* x1h = (u16*)WSK(0);          // + z*2097152 elems
    // ws [8,11M): wqh (S1-S2) -> td1 ws[8,12) (S7-)
    u16* wqh = (u16*)WSK(8192);       // + z*786432 elems
    u16* td1 = (u16*)WSK(8192);
    // ws [11,13M): w1h, w2h (S1-S6); td2 ws[12,16) (S7-)
    u16* w1h = (u16*)WSK(11264);      // + z*262144 elems
    u16* w2h = (u16*)WSK(12288);      // + z*262144 elems
    u16* td2 = (u16*)WSK(12288);
    // ws [13,37M): qkvB (S2-S3)
    u16* qkvB = (u16*)WSK(13312);     // [z][4096][1536]
    // ws [16,24M): x1l z0/z1 (S4-S7)
    u16* x1l = (u16*)WSK(16384);      // + z*2097152 elems
    // ws [24,40M): ffo hi/lo (S6-S7)
    u16* ffo0h = (u16*)WSK(24576);
    u16* ffo0l = (u16*)WSK(28672);
    u16* ffo1h = (u16*)WSK(32768);
    u16* ffo1l = (u16*)WSK(36864);
    // d_out: AO0/AO1 f32 (S3-S4); h hi/lo (S5-S6); final out (S8)
    float* AO0 = (float*)OBK(0);
    float* AO1 = (float*)OBK(8192);
    u16* h0h = (u16*)OBK(0);
    u16* h0l = (u16*)OBK(4096);
    u16* h1h = (u16*)OBK(8192);
    u16* h1l = (u16*)OBK(12288);
    float* out = (float*)d_out;

    // S0: x split
    convert_x<<<2048, 256, 0, stream>>>(x, xhi, xlo);
    // S1: weight transposes (hi only)
    convert_wt<<<dim3(16, 48, 2), 256, 0, stream>>>(wqkv[0], wqkv[1], wqh, 786432, 1536);
    convert_wt<<<dim3(16, 16, 2), 256, 0, stream>>>(w1[0], w1[1], w1h, 262144, 512);
    convert_wt<<<dim3(16, 16, 2), 256, 0, stream>>>(w2[0], w2[1], w2h, 262144, 512);
    // S2: qkv gemm — permuted-B, linear output into qkvB
    gemm_split<128, 0><<<dim3(32, 12, 2), 256, 0, stream>>>(
        xhi, xlo, 0, wqh, 786432, bqkv[0], bqkv[1], 1536,
        qkvB, qkvB, nullptr, nullptr);
    // S3: attention (z=0 causal, z=1 anti-causal)
    attn_mfma<<<dim3(32, 16, 2), 256, 0, stream>>>(qkvB, AO0, AO1);
    // S4: add + LN -> x1 hi/lo
    add_ln_a<<<dim3(1024, 1, 2), 256, 0, stream>>>(x, AO0, AO1,
        ga[0], ga[1], bea[0], bea[1], x1h, x1l, 2097152);
    // S5: ff1 (gelu) -> h hi/lo (in d_out)
    gemm_split<64, 1><<<dim3(64, 4, 2), 256, 0, stream>>>(
        x1h, x1l, 2097152, w1h, 262144, b1[0], b1[1], 512,
        h0h, h1h, h0l, h1l);
    // S6: ff2 -> ffo hi/lo (in ws)
    gemm_split<64, 2><<<dim3(64, 4, 2), 256, 0, stream>>>(
        h0h, h0l, 2097152, w2h, 262144, b2[0], b2[1], 512,
        ffo0h, ffo1h, ffo0l, ffo1l);
    // S7: add + LN + sigmoid -> td
    add_ln_b<<<dim3(1024, 1, 2), 256, 0, stream>>>(
        x1h, x1l, 2097152, ffo0h, ffo1h, ffo0l, ffo1l,
        gb[0], gb[1], beb[0], beb[1], td1, td2);
    // S8: sim
    sim_mfma<<<dim3(8, 8, 4), 256, 0, stream>>>(td1, td2, out);
}

// Round 13
// 147.864 us; speedup vs baseline: 1.2285x; 1.0863x over previous
//
#include <hip/hip_runtime.h>
#include <math.h>

// ---------------------------------------------------------------------------
// bf16-MFMA implementation, both layers merged (z=2), global_load_lds staging.
//  - qkv GEMM: 2-term split (x hi/lo × w hi) — proven numerics
//  - R13: FF path 1-term single-bf16 (x1/h/ffo) — sim's 512-mean damps
//    uncorrelated td errors by ~45x, so FF truncation is invisible at sim.
//  - R13: sim 64x128 tiles (512 blocks, 2-3/CU vs 1/CU before)
//  - attention: R12 att[2] pipeline (swapped QK^T, in-reg P, defer-max, setprio)
// ---------------------------------------------------------------------------

typedef float f32x4 __attribute__((ext_vector_type(4)));
typedef short s16x8 __attribute__((ext_vector_type(8)));
typedef int   i32x4 __attribute__((ext_vector_type(4)));
typedef unsigned short u16;
typedef unsigned int u32;

#define NTOK 1024
#define PL 512
#define QSCALE 0.04419417382415922f  // 1/sqrt(512)

__device__ inline u16 f2bf(float f) {
    unsigned u = __builtin_bit_cast(unsigned, f);
    unsigned r = u + 0x7fffu + ((u >> 16) & 1u);   // RNE
    return (u16)(r >> 16);
}
__device__ inline float bf2f(u16 h) {
    unsigned u = ((unsigned)h) << 16;
    return __builtin_bit_cast(float, u);
}
__device__ inline u32 cvtpk(float a, float b) {   // lo=a, hi=b (RNE)
    u32 r;
    asm("v_cvt_pk_bf16_f32 %0, %1, %2" : "=v"(r) : "v"(a), "v"(b));
    return r;
}

__device__ inline void gll16(const void* g, void* l) {
    __builtin_amdgcn_global_load_lds(
        (const __attribute__((address_space(1))) u32*)g,
        (__attribute__((address_space(3))) u32*)l, 16, 0, 0);
}

// ---------------------------------------------------------------------------
// x -> hi/lo bf16 split (elementwise)
// ---------------------------------------------------------------------------
__global__ __launch_bounds__(256) void convert_x(const float* __restrict__ X,
    u16* __restrict__ hi, u16* __restrict__ lo)
{
    const int i = (blockIdx.x * 256 + threadIdx.x) * 4;
    float4 v = *(const float4*)&X[i];
    float vv[4] = {v.x, v.y, v.z, v.w};
    #pragma unroll
    for (int j = 0; j < 4; j++) {
        u16 h = f2bf(vv[j]);
        hi[i + j] = h;
        lo[i + j] = f2bf(vv[j] - bf2f(h));
    }
}

// ---------------------------------------------------------------------------
// W [512][N] f32 -> Wt [N][512] bf16 hi (tiled transpose), z = layer
// ---------------------------------------------------------------------------
__global__ __launch_bounds__(256) void convert_wt(const float* __restrict__ W0,
    const float* __restrict__ W1, u16* __restrict__ WhiB, const size_t dLS, const int N)
{
    const float* W = blockIdx.z ? W1 : W0;
    u16* Whi = WhiB + (size_t)blockIdx.z * dLS;
    __shared__ float T[32][36];
    const int k0 = blockIdx.x * 32, n0 = blockIdx.y * 32;
    const int tr = threadIdx.x >> 3, tc = (threadIdx.x & 7) * 4;
    *(float4*)&T[tr][tc] = *(const float4*)&W[(size_t)(k0 + tr) * N + n0 + tc];
    __syncthreads();
    const size_t o = (size_t)(n0 + tr) * 512 + k0 + tc;
    #pragma unroll
    for (int j = 0; j < 4; j++) Whi[o + j] = f2bf(T[tc + j][tr]);
}

// π: permuted col j -> original col (head-fast split c2 = dd*8+h)
__device__ inline int qkv_perm(int j) {
    return (j >> 9) * 512 + ((j & 63) << 3) + ((j >> 6) & 7);
}

// ---------------------------------------------------------------------------
// MFMA GEMM, z = layer. A[4096][512] x Bt[N][512] (hi).
// SPLIT_A: 1 = A hi/lo 2-term, 0 = plain 1-term.
// EPI: 0 = qkv (B rows permuted, linear output, Q scaled),
//      1 = gelu -> single bf16, 2 = plain single bf16.
// BK=32; dbuf gll staging (stage kt+1 before compute kt, 1 barrier).
// ---------------------------------------------------------------------------
template<int BM, int SPLIT_A, int EPI>
__global__ __launch_bounds__(256) void gemm_split(
    const u16* __restrict__ AhiB, const u16* __restrict__ AloB, const size_t aLS,
    const u16* __restrict__ BhiB, const size_t bLS,
    const float* __restrict__ bias0, const float* __restrict__ bias1, const int Ncols,
    u16* __restrict__ oh0, u16* __restrict__ oh1)
{
    constexpr int FM = BM / 32;
    __shared__ u16 Ah[2][BM * 32];
    __shared__ u16 Al[SPLIT_A ? 2 * BM * 32 : 64];
    __shared__ u16 Bh[2][128 * 32];
    const int z = blockIdx.z;
    const u16* Ahi = AhiB + (size_t)z * aLS;
    const u16* Alo = SPLIT_A ? (AloB + (size_t)z * aLS) : nullptr;
    const u16* Bhi = BhiB + (size_t)z * bLS;
    const float* bias = z ? bias1 : bias0;
    u16* oh = z ? oh1 : oh0;

    const int t = threadIdx.x, l = t & 63, w = t >> 6;
    const int lr = l & 15, lg = l >> 4;
    const int wm = w >> 1, wn = w & 1;
    const int m0 = blockIdx.x * BM, n0 = blockIdx.y * 128;
    const int srow = l >> 2, sch = l & 3;    // staging lane coords (16 rows/KB)

    f32x4 acc[FM][4];
    #pragma unroll
    for (int i = 0; i < FM; i++)
        #pragma unroll
        for (int j = 0; j < 4; j++) acc[i][j] = f32x4{0.f, 0.f, 0.f, 0.f};

    auto stage = [&](int bufi, int k0) {
        #pragma unroll
        for (int i = 0; i < BM / 64; i++) {
            const int j = w * (BM / 64) + i;
            const int r = j * 16 + srow;
            const int ck = sch ^ ((r >> 1) & 3);
            const size_t g = (size_t)(m0 + r) * 512 + k0 + ck * 8;
            gll16(&Ahi[g], &Ah[bufi][j * 512]);
            if constexpr (SPLIT_A) gll16(&Alo[g], &Al[bufi * BM * 32 + j * 512]);
        }
        #pragma unroll
        for (int i = 0; i < 2; i++) {
            const int j = w * 2 + i;
            const int r = j * 16 + srow;
            const int ck = sch ^ ((r >> 1) & 3);
            const int brow = (EPI == 0) ? qkv_perm(n0 + r) : (n0 + r);
            gll16(&Bhi[(size_t)brow * 512 + k0 + ck * 8], &Bh[bufi][j * 512]);
        }
    };

    stage(0, 0);
    __syncthreads();
    int buf = 0;
    for (int kt = 0; kt < 16; kt++) {
        if (kt < 15) stage(buf ^ 1, (kt + 1) * 32);

        s16x8 ah[FM], al[FM];
        #pragma unroll
        for (int fm = 0; fm < FM; fm++) {
            const int r = wm * (BM / 2) + fm * 16 + lr;
            const int d = r * 32 + ((lg ^ ((r >> 1) & 3)) << 3);
            ah[fm] = *(const s16x8*)&Ah[buf][d];
            if constexpr (SPLIT_A) al[fm] = *(const s16x8*)&Al[buf * BM * 32 + d];
        }
        #pragma unroll
        for (int fn = 0; fn < 4; fn++) {
            const int r = wn * 64 + fn * 16 + lr;
            const int d = r * 32 + ((lg ^ ((r >> 1) & 3)) << 3);
            s16x8 bh = *(const s16x8*)&Bh[buf][d];
            #pragma unroll
            for (int fm = 0; fm < FM; fm++) {
                acc[fm][fn] = __builtin_amdgcn_mfma_f32_16x16x32_bf16(ah[fm], bh, acc[fm][fn], 0, 0, 0);
                if constexpr (SPLIT_A)
                    acc[fm][fn] = __builtin_amdgcn_mfma_f32_16x16x32_bf16(al[fm], bh, acc[fm][fn], 0, 0, 0);
            }
        }
        __syncthreads();   // waves done with buf; stage(buf^1) drained
        buf ^= 1;
    }
    // epilogue
    #pragma unroll
    for (int fm = 0; fm < FM; fm++)
        #pragma unroll
        for (int fn = 0; fn < 4; fn++)
            #pragma unroll
            for (int rg = 0; rg < 4; rg++) {
                const int r = m0 + wm * (BM / 2) + fm * 16 + lg * 4 + rg;
                const int c = n0 + wn * 64 + fn * 16 + lr;
                if constexpr (EPI == 0) {
                    float v = acc[fm][fn][rg] + bias[qkv_perm(c)];
                    if (c < 512) v *= QSCALE;   // Q third (uniform per block)
                    oh[((size_t)z * 4096 + r) * Ncols + c] = f2bf(v);
                } else {
                    float gl = acc[fm][fn][rg] + bias[c];
                    if constexpr (EPI == 1)
                        gl = 0.5f * gl * (1.f + erff(gl * 0.70710678118654752f));
                    oh[(size_t)r * Ncols + c] = f2bf(gl);
                }
            }
}

// ---------------------------------------------------------------------------
// Flash attention, bf16 MFMA, z = layer (z==0 causal, z==1 anti-causal).
// R12 structure: att[2] pipeline — QK(t+1) -> PV(t) -> SM(t+1); swapped QK^T,
// lane-local softmax, in-register P, defer-max, setprio. (unchanged)
// ---------------------------------------------------------------------------
__global__ __launch_bounds__(256) void attn_mfma(const u16* __restrict__ QKV,
    float* __restrict__ AO0, float* __restrict__ AO1)
{
    __shared__ u16 Ks[2][64 * 64];
    __shared__ u16 Vs[2][64 * 64];
    const int t = threadIdx.x, l = t & 63, w = t >> 6;
    const int lr = l & 15, lg = l >> 4;
    const int z = blockIdx.z;
    const int causal = (z == 0);
    const int bh = blockIdx.x;
    const int b = bh >> 3, h = bh & 7;
    const int qt = causal ? (15 - (int)blockIdx.y) : (int)blockIdx.y;  // long jobs first
    const u16* base = QKV + ((size_t)z * 4096 + (size_t)b * NTOK) * 1536;
    float* AO = z ? AO1 : AO0;
    const int q0 = qt * 64 + w * 16;

    s16x8 aq[2];
    aq[0] = *(const s16x8*)&base[(size_t)(q0 + lr) * 1536 + h * 64 + lg * 8];
    aq[1] = *(const s16x8*)&base[(size_t)(q0 + lr) * 1536 + h * 64 + 32 + lg * 8];

    f32x4 o[4];
    float m_ = -INFINITY, l_ = 0.f;
    #pragma unroll
    for (int f = 0; f < 4; f++) o[f] = f32x4{0.f, 0.f, 0.f, 0.f};

    const int kt0 = causal ? 0 : qt, kt1 = causal ? qt : 15;

    auto stageK = [&](int kt) {
        #pragma unroll
        for (int i = 0; i < 2; i++) {
            const int j = w * 2 + i;
            const int r = j * 8 + (l >> 3);
            const int ck = (l & 7) ^ (r & 7);
            gll16(&base[(size_t)(kt * 64 + r) * 1536 + 512 + h * 64 + ck * 8],
                  &Ks[kt & 1][j * 512]);
        }
    };
    const int jv = t & 63;
    s16x8 va, vb;
    auto loadV = [&](int kt) {
        const u16* vr = &base[(size_t)(kt * 64 + jv) * 1536 + 1024 + h * 64 + w * 16];
        va = *(const s16x8*)&vr[0];
        vb = *(const s16x8*)&vr[8];
    };
    auto writeV = [&](int kt) {
        #pragma unroll
        for (int i = 0; i < 8; i++) {
            const int d = w * 16 + i;
            Vs[kt & 1][d * 64 + (((jv >> 3) ^ (d & 7)) << 3) + (jv & 7)] = (u16)va[i];
        }
        #pragma unroll
        for (int i = 0; i < 8; i++) {
            const int d = w * 16 + 8 + i;
            Vs[kt & 1][d * 64 + (((jv >> 3) ^ (d & 7)) << 3) + (jv & 7)] = (u16)vb[i];
        }
    };

    s16x8 pap[2];
    float psc[4] = {1.f, 1.f, 1.f, 1.f};
    int pneed = 1;

    auto QK = [&](int kt, f32x4* s) {
        #pragma unroll
        for (int f = 0; f < 4; f++) s[f] = f32x4{0.f, 0.f, 0.f, 0.f};
        #pragma unroll
        for (int kk = 0; kk < 2; kk++)
            #pragma unroll
            for (int f = 0; f < 4; f++) {
                const int row = f * 16 + lr;
                const int ch = kk * 4 + lg;
                s16x8 bk = *(const s16x8*)&Ks[kt & 1][row * 64 + ((ch ^ (row & 7)) << 3)];
                s[f] = __builtin_amdgcn_mfma_f32_16x16x32_bf16(bk, aq[kk], s[f], 0, 0, 0);
            }
        if (kt == qt) {
            const int q = q0 + lr;
            #pragma unroll
            for (int f = 0; f < 4; f++)
                #pragma unroll
                for (int r = 0; r < 4; r++) {
                    const int key = kt * 64 + f * 16 + lg * 4 + r;
                    if (causal ? (key > q) : (key < q)) s[f][r] = -INFINITY;
                }
        }
    };

    auto SM = [&](f32x4* s) {
        float rm = s[0][0];
        #pragma unroll
        for (int f = 0; f < 4; f++)
            #pragma unroll
            for (int r = 0; r < 4; r++) rm = fmaxf(rm, s[f][r]);
        rm = fmaxf(rm, __shfl_xor(rm, 16));
        rm = fmaxf(rm, __shfl_xor(rm, 32));
        pneed = !__all(rm <= m_ + 8.f);          // defer-max (T13)
        const float mn = pneed ? fmaxf(m_, rm) : m_;
        const float sc = __expf(m_ - mn);        // ==1 when deferred
        float ps = 0.f;
        #pragma unroll
        for (int f = 0; f < 4; f++)
            #pragma unroll
            for (int r = 0; r < 4; r++) {
                float p = __expf(s[f][r] - mn);
                s[f][r] = p;
                ps += p;
            }
        ps += __shfl_xor(ps, 16);
        ps += __shfl_xor(ps, 32);
        l_ = l_ * sc + ps;
        m_ = mn;
        u32 P01[4], P23[4];
        #pragma unroll
        for (int f = 0; f < 4; f++) {
            P01[f] = cvtpk(s[f][0], s[f][1]);
            P23[f] = cvtpk(s[f][2], s[f][3]);
        }
        const int srcA = lr + ((lg & 1) << 5);
        const int srcB = srcA + 16;
        #pragma unroll
        for (int kk = 0; kk < 2; kk++) {
            const u32 a01_0 = (u32)__shfl((int)P01[2 * kk], srcA);
            const u32 a01_1 = (u32)__shfl((int)P01[2 * kk + 1], srcA);
            const u32 a23_0 = (u32)__shfl((int)P23[2 * kk], srcA);
            const u32 a23_1 = (u32)__shfl((int)P23[2 * kk + 1], srcA);
            const u32 b01_0 = (u32)__shfl((int)P01[2 * kk], srcB);
            const u32 b01_1 = (u32)__shfl((int)P01[2 * kk + 1], srcB);
            const u32 b23_0 = (u32)__shfl((int)P23[2 * kk], srcB);
            const u32 b23_1 = (u32)__shfl((int)P23[2 * kk + 1], srcB);
            i32x4 av;
            av[0] = (int)((lg & 2) ? a01_1 : a01_0);
            av[1] = (int)((lg & 2) ? a23_1 : a23_0);
            av[2] = (int)((lg & 2) ? b01_1 : b01_0);
            av[3] = (int)((lg & 2) ? b23_1 : b23_0);
            pap[kk] = __builtin_bit_cast(s16x8, av);
        }
        if (pneed) {
            #pragma unroll
            for (int r = 0; r < 4; r++) psc[r] = __shfl(sc, lg * 4 + r);
        }
    };

    auto PV = [&](int kt) {
        if (pneed) {
            #pragma unroll
            for (int r = 0; r < 4; r++)
                #pragma unroll
                for (int f = 0; f < 4; f++) o[f][r] *= psc[r];
        }
        #pragma unroll
        for (int kk = 0; kk < 2; kk++)
            #pragma unroll
            for (int f = 0; f < 4; f++) {
                const int row = f * 16 + lr;
                const int ch = kk * 4 + lg;
                s16x8 bv = *(const s16x8*)&Vs[kt & 1][row * 64 + ((ch ^ (row & 7)) << 3)];
                o[f] = __builtin_amdgcn_mfma_f32_16x16x32_bf16(pap[kk], bv, o[f], 0, 0, 0);
            }
    };

    // ---- prologue ----
    stageK(kt0);
    if (kt0 < kt1) stageK(kt0 + 1);
    loadV(kt0);
    writeV(kt0);
    __syncthreads();
    {
        f32x4 s0[4];
        QK(kt0, s0);
        SM(s0);
    }
    __syncthreads();

    // ---- main loop: QK(t+1) -> PV(t) -> SM(t+1) ----
    for (int kt = kt0; kt <= kt1; kt++) {
        if (kt + 2 <= kt1) stageK(kt + 2);
        if (kt + 1 <= kt1) loadV(kt + 1);
        f32x4 sn[4];
        __builtin_amdgcn_s_setprio(1);
        if (kt + 1 <= kt1) QK(kt + 1, sn);
        PV(kt);
        __builtin_amdgcn_s_setprio(0);
        if (kt + 1 <= kt1) {
            SM(sn);
            writeV(kt + 1);
        }
        __syncthreads();
    }

    // ---- epilogue ----
    const float linv = 1.f / l_;
    #pragma unroll
    for (int r = 0; r < 4; r++) {
        const float lv = __shfl(linv, lg * 4 + r);
        #pragma unroll
        for (int f = 0; f < 4; f++)
            AO[(size_t)(b * NTOK + q0 + lg * 4 + r) * PL + h * 64 + f * 16 + lr] = o[f][r] * lv;
    }
}

// ---------------------------------------------------------------------------
// add+LN A: x(f32)+attn(f32) -> LN -> single bf16 x1. z = layer.
// ---------------------------------------------------------------------------
__global__ __launch_bounds__(256) void add_ln_a(const float* __restrict__ X,
    const float* __restrict__ A0, const float* __restrict__ A1,
    const float* __restrict__ g0, const float* __restrict__ g1,
    const float* __restrict__ be0, const float* __restrict__ be1,
    u16* __restrict__ OB, const size_t oLS)
{
    const int z = blockIdx.z;
    const float* A = z ? A1 : A0;
    const float* g = z ? g1 : g0;
    const float* be = z ? be1 : be0;
    u16* O = OB + (size_t)z * oLS;
    const int row = blockIdx.x * 4 + (threadIdx.x >> 6);
    const int lane = threadIdx.x & 63;
    const float* xr = X + (size_t)row * PL;
    const float* ar = A + (size_t)row * PL;
    float v[8];
    float sum = 0.f;
    #pragma unroll
    for (int u = 0; u < 8; u++) { v[u] = xr[lane + u * 64] + ar[lane + u * 64]; sum += v[u]; }
    #pragma unroll
    for (int o = 32; o > 0; o >>= 1) sum += __shfl_xor(sum, o);
    const float mu = sum * (1.f / 512.f);
    float s2 = 0.f;
    #pragma unroll
    for (int u = 0; u < 8; u++) { float d = v[u] - mu; s2 = fmaf(d, d, s2); }
    #pragma unroll
    for (int o = 32; o > 0; o >>= 1) s2 += __shfl_xor(s2, o);
    const float rstd = rsqrtf(s2 * (1.f / 512.f) + 1e-5f);
    #pragma unroll
    for (int u = 0; u < 8; u++) {
        const int c = lane + u * 64;
        O[(size_t)row * PL + c] = f2bf((v[u] - mu) * rstd * g[c] + be[c]);
    }
}

// ---------------------------------------------------------------------------
// add+LN B: x1(bf16) + ffo(bf16) -> LN -> sigmoid -> bf16 td. z = layer.
// ---------------------------------------------------------------------------
__global__ __launch_bounds__(256) void add_ln_b(
    const u16* __restrict__ X1B, const size_t xLS,
    const u16* __restrict__ FB, const size_t fLS,
    const float* __restrict__ g0, const float* __restrict__ g1,
    const float* __restrict__ be0, const float* __restrict__ be1,
    u16* __restrict__ TDB, const size_t tLS)
{
    const int z = blockIdx.z;
    const u16* X1 = X1B + (size_t)z * xLS;
    const u16* F = FB + (size_t)z * fLS;
    const float* g = z ? g1 : g0;
    const float* be = z ? be1 : be0;
    u16* TD = TDB + (size_t)z * tLS;
    const int row = blockIdx.x * 4 + (threadIdx.x >> 6);
    const int lane = threadIdx.x & 63;
    const size_t ro = (size_t)row * PL;
    float v[8];
    float sum = 0.f;
    #pragma unroll
    for (int u = 0; u < 8; u++) {
        const int c = lane + u * 64;
        v[u] = bf2f(X1[ro + c]) + bf2f(F[ro + c]);
        sum += v[u];
    }
    #pragma unroll
    for (int o = 32; o > 0; o >>= 1) sum += __shfl_xor(sum, o);
    const float mu = sum * (1.f / 512.f);
    float s2 = 0.f;
    #pragma unroll
    for (int u = 0; u < 8; u++) { float d = v[u] - mu; s2 = fmaf(d, d, s2); }
    #pragma unroll
    for (int o = 32; o > 0; o >>= 1) s2 += __shfl_xor(s2, o);
    const float rstd = rsqrtf(s2 * (1.f / 512.f) + 1e-5f);
    #pragma unroll
    for (int u = 0; u < 8; u++) {
        const int c = lane + u * 64;
        float y = (v[u] - mu) * rstd * g[c] + be[c];
        TD[ro + c] = f2bf(1.f / (1.f + expf(-y)));
    }
}

// ---------------------------------------------------------------------------
// sim: per batch, C[i][j] = dot(td1[i,:], td2[j,:]) / 512  (plain bf16 MFMA)
// R13: 64x128 tiles -> 512 blocks (2-3/CU). gll-staged, BK=64, dbuf.
// ---------------------------------------------------------------------------
__global__ __launch_bounds__(256) void sim_mfma(const u16* __restrict__ TD1,
    const u16* __restrict__ TD2, float* __restrict__ Out)
{
    __shared__ u16 Ah[2][64 * 64], Bh[2][128 * 64];
    const int t = threadIdx.x, l = t & 63, w = t >> 6;
    const int lr = l & 15, lg = l >> 4;
    const int wm = w >> 1, wn = w & 1;
    const int bz = blockIdx.z;
    const u16* A = TD1 + (size_t)bz * NTOK * PL;
    const u16* B = TD2 + (size_t)bz * NTOK * PL;
    const int m0 = blockIdx.x * 64, n0 = blockIdx.y * 128;

    f32x4 acc[2][4];
    #pragma unroll
    for (int i = 0; i < 2; i++)
        #pragma unroll
        for (int j = 0; j < 4; j++) acc[i][j] = f32x4{0.f, 0.f, 0.f, 0.f};

    auto stage = [&](int bufi, int k0) {
        #pragma unroll
        for (int i = 0; i < 2; i++) {           // A: 8 KB = 8 chunks
            const int j = w * 2 + i;
            const int r = j * 8 + (l >> 3);
            const int ck = (l & 7) ^ (r & 7);
            gll16(&A[(size_t)(m0 + r) * 512 + k0 + ck * 8], &Ah[bufi][j * 512]);
        }
        #pragma unroll
        for (int i = 0; i < 4; i++) {           // B: 16 KB = 16 chunks
            const int j = w * 4 + i;
            const int r = j * 8 + (l >> 3);
            const int ck = (l & 7) ^ (r & 7);
            gll16(&B[(size_t)(n0 + r) * 512 + k0 + ck * 8], &Bh[bufi][j * 512]);
        }
    };

    stage(0, 0);
    __syncthreads();
    int buf = 0;
    for (int kt = 0; kt < 8; kt++) {
        if (kt < 7) stage(buf ^ 1, (kt + 1) * 64);
        #pragma unroll
        for (int kk = 0; kk < 2; kk++) {
            const int ch = kk * 4 + lg;
            s16x8 af[2], bf[4];
            #pragma unroll
            for (int fm = 0; fm < 2; fm++) {
                const int r = wm * 32 + fm * 16 + lr;
                af[fm] = *(const s16x8*)&Ah[buf][r * 64 + ((ch ^ (r & 7)) << 3)];
            }
            #pragma unroll
            for (int fn = 0; fn < 4; fn++) {
                const int r = wn * 64 + fn * 16 + lr;
                bf[fn] = *(const s16x8*)&Bh[buf][r * 64 + ((ch ^ (r & 7)) << 3)];
            }
            #pragma unroll
            for (int fm = 0; fm < 2; fm++)
                #pragma unroll
                for (int fn = 0; fn < 4; fn++)
                    acc[fm][fn] = __builtin_amdgcn_mfma_f32_16x16x32_bf16(af[fm], bf[fn], acc[fm][fn], 0, 0, 0);
        }
        __syncthreads();
        buf ^= 1;
    }
    #pragma unroll
    for (int fm = 0; fm < 2; fm++)
        #pragma unroll
        for (int fn = 0; fn < 4; fn++)
            #pragma unroll
            for (int rg = 0; rg < 4; rg++) {
                const int r = m0 + wm * 32 + fm * 16 + lg * 4 + rg;
                const int c = n0 + wn * 64 + fn * 16 + lr;
                Out[((size_t)(bz * NTOK + r)) * NTOK + c] = acc[fm][fn][rg] * (1.f / 512.f);
            }
}

// ---------------------------------------------------------------------------
extern "C" void kernel_launch(void* const* d_in, const int* in_sizes, int n_in,
                              void* d_out, int out_size, void* d_ws, size_t ws_size,
                              hipStream_t stream)
{
    const float* x = (const float*)d_in[0];
    const float* wqkv[2] = {(const float*)d_in[1],  (const float*)d_in[11]};
    const float* bqkv[2] = {(const float*)d_in[2],  (const float*)d_in[12]};
    const float* ga[2]   = {(const float*)d_in[3],  (const float*)d_in[13]};
    const float* bea[2]  = {(const float*)d_in[4],  (const float*)d_in[14]};
    const float* w1[2]   = {(const float*)d_in[5],  (const float*)d_in[15]};
    const float* b1[2]   = {(const float*)d_in[6],  (const float*)d_in[16]};
    const float* w2[2]   = {(const float*)d_in[7],  (const float*)d_in[17]};
    const float* b2[2]   = {(const float*)d_in[8],  (const float*)d_in[18]};
    const float* gb[2]   = {(const float*)d_in[9],  (const float*)d_in[19]};
    const float* beb[2]  = {(const float*)d_in[10], (const float*)d_in[20]};

    // -------- workspace map (KB offsets; lifetimes verified stage-by-stage) --
    char* wsb = (char*)d_ws;
    char* ob  = (char*)d_out;
    #define WSK(kb) ((char*)wsb + ((size_t)(kb) << 10))
    #define OBK(kb) ((char*)ob  + ((size_t)(kb) << 10))
    // ws [0,8M):  xhi/xlo (S0-S2)  -> x1 single bf16 z0/z1 (S4-S7)
    u16* xhi = (u16*)WSK(0);
    u16* xlo = (u16*)WSK(4096);
    u16* x1  = (u16*)WSK(0);          // + z*2097152 elems
    // ws [8,11M): wqh (S1-S2) -> td (S7-): td1 [8,12M), td2 [12,16M)
    u16* wqh = (u16*)WSK(8192);       // + z*786432 elems
    u16* td1 = (u16*)WSK(8192);
    u16* td2 = (u16*)WSK(12288);
    // ws [11,13M): w1h [11,12M), w2h [12,13M) (S1-S6; dead before td writes)
    u16* w1h = (u16*)WSK(11264);      // + z*262144 elems
    u16* w2h = (u16*)WSK(12288);      // + z*262144 elems
    // ws [13,37M): qkvB (S2-S3)
    u16* qkvB = (u16*)WSK(13312);     // [z][4096][1536]
    // ws [24,32M): ffo single bf16 (S6-S7; qkvB dead)
    u16* ffo = (u16*)WSK(24576);      // + z*2097152 elems
    // d_out: AO0/AO1 f32 (S3-S4); h bf16 (S5-S6); final out (S8)
    float* AO0 = (float*)OBK(0);
    float* AO1 = (float*)OBK(8192);
    u16* hB = (u16*)OBK(0);           // + z*2097152 elems
    float* out = (float*)d_out;

    // S0: x split
    convert_x<<<2048, 256, 0, stream>>>(x, xhi, xlo);
    // S1: weight transposes (hi only)
    convert_wt<<<dim3(16, 48, 2), 256, 0, stream>>>(wqkv[0], wqkv[1], wqh, 786432, 1536);
    convert_wt<<<dim3(16, 16, 2), 256, 0, stream>>>(w1[0], w1[1], w1h, 262144, 512);
    convert_wt<<<dim3(16, 16, 2), 256, 0, stream>>>(w2[0], w2[1], w2h, 262144, 512);
    // S2: qkv gemm — 2-term, permuted-B, linear output into qkvB
    gemm_split<128, 1, 0><<<dim3(32, 12, 2), 256, 0, stream>>>(
        xhi, xlo, 0, wqh, 786432, bqkv[0], bqkv[1], 1536,
        qkvB, qkvB);
    // S3: attention (z=0 causal, z=1 anti-causal)
    attn_mfma<<<dim3(32, 16, 2), 256, 0, stream>>>(qkvB, AO0, AO1);
    // S4: add + LN -> x1 single bf16
    add_ln_a<<<dim3(1024, 1, 2), 256, 0, stream>>>(x, AO0, AO1,
        ga[0], ga[1], bea[0], bea[1], x1, 2097152);
    // S5: ff1 (gelu) -> h bf16 (d_out), 1-term
    gemm_split<64, 0, 1><<<dim3(64, 4, 2), 256, 0, stream>>>(
        x1, nullptr, 2097152, w1h, 262144, b1[0], b1[1], 512,
        hB, hB + 2097152);
    // S6: ff2 -> ffo bf16 (ws), 1-term
    gemm_split<64, 0, 2><<<dim3(64, 4, 2), 256, 0, stream>>>(
        hB, nullptr, 2097152, w2h, 262144, b2[0], b2[1], 512,
        ffo, ffo + 2097152);
    // S7: add + LN + sigmoid -> td
    add_ln_b<<<dim3(1024, 1, 2), 256, 0, stream>>>(
        x1, 2097152, ffo, 2097152,
        gb[0], gb[1], beb[0], beb[1], td1, 2097152);
    // S8: sim (64x128 tiles, 512 blocks)
    sim_mfma<<<dim3(16, 8, 4), 256, 0, stream>>>(td1, td2, out);
}

// Round 14
// 128.512 us; speedup vs baseline: 1.4135x; 1.1506x over previous
//
#include <hip/hip_runtime.h>
#include <math.h>

// ---------------------------------------------------------------------------
// bf16-MFMA implementation, both layers merged (z=2), global_load_lds staging.
//  - R14: ALL GEMMs 1-term plain bf16 (qkv x-lo dropped — R7 evidence: the
//    symmetric w-lo drop left absmax bit-identical; score noise ~6e-5 at out).
//  - R14: single merged prep dispatch (x convert + 3 weight transposes).
//  - qkv linear [z][4096][1536] output via permuted weight rows (R10)
//  - attention: R12 att[2] pipeline (swapped QK^T, in-reg P, defer-max, setprio)
//  - sim 64x128 tiles (R13)
// ---------------------------------------------------------------------------

typedef float f32x4 __attribute__((ext_vector_type(4)));
typedef short s16x8 __attribute__((ext_vector_type(8)));
typedef int   i32x4 __attribute__((ext_vector_type(4)));
typedef unsigned short u16;
typedef unsigned int u32;

#define NTOK 1024
#define PL 512
#define QSCALE 0.04419417382415922f  // 1/sqrt(512)

__device__ inline u16 f2bf(float f) {
    unsigned u = __builtin_bit_cast(unsigned, f);
    unsigned r = u + 0x7fffu + ((u >> 16) & 1u);   // RNE
    return (u16)(r >> 16);
}
__device__ inline float bf2f(u16 h) {
    unsigned u = ((unsigned)h) << 16;
    return __builtin_bit_cast(float, u);
}
__device__ inline u32 cvtpk(float a, float b) {   // lo=a, hi=b (RNE)
    u32 r;
    asm("v_cvt_pk_bf16_f32 %0, %1, %2" : "=v"(r) : "v"(a), "v"(b));
    return r;
}

__device__ inline void gll16(const void* g, void* l) {
    __builtin_amdgcn_global_load_lds(
        (const __attribute__((address_space(1))) u32*)g,
        (__attribute__((address_space(3))) u32*)l, 16, 0, 0);
}

// ---------------------------------------------------------------------------
// Merged prep: blockIdx ranges -> {x->bf16, wqkv^T, w1^T, w2^T}
//   [0,2048): x convert (hi only)
//   [2048,3584): wqkv transpose (z major 768)
//   [3584,4096): w1 transpose (z major 256)
//   [4096,4608): w2 transpose (z major 256)
// ---------------------------------------------------------------------------
__global__ __launch_bounds__(256) void prep(const float* __restrict__ X,
    u16* __restrict__ xhi,
    const float* __restrict__ Wq0, const float* __restrict__ Wq1, u16* __restrict__ wqh,
    const float* __restrict__ W10, const float* __restrict__ W11, u16* __restrict__ w1h,
    const float* __restrict__ W20, const float* __restrict__ W21, u16* __restrict__ w2h)
{
    const int bid = blockIdx.x;
    if (bid < 2048) {
        const int i = (bid * 256 + threadIdx.x) * 4;
        float4 v = *(const float4*)&X[i];
        xhi[i + 0] = f2bf(v.x); xhi[i + 1] = f2bf(v.y);
        xhi[i + 2] = f2bf(v.z); xhi[i + 3] = f2bf(v.w);
        return;
    }
    const float* W;
    u16* Whi;
    int N, kx, ny;
    if (bid < 3584) {
        const int idx = bid - 2048;
        const int z = idx / 768, rem = idx % 768;
        kx = rem % 16; ny = rem / 16;
        W = z ? Wq1 : Wq0; Whi = wqh + (size_t)z * 786432; N = 1536;
    } else if (bid < 4096) {
        const int idx = bid - 3584;
        const int z = idx / 256, rem = idx % 256;
        kx = rem % 16; ny = rem / 16;
        W = z ? W11 : W10; Whi = w1h + (size_t)z * 262144; N = 512;
    } else {
        const int idx = bid - 4096;
        const int z = idx / 256, rem = idx % 256;
        kx = rem % 16; ny = rem / 16;
        W = z ? W21 : W20; Whi = w2h + (size_t)z * 262144; N = 512;
    }
    __shared__ float T[32][36];
    const int k0 = kx * 32, n0 = ny * 32;
    const int tr = threadIdx.x >> 3, tc = (threadIdx.x & 7) * 4;
    *(float4*)&T[tr][tc] = *(const float4*)&W[(size_t)(k0 + tr) * N + n0 + tc];
    __syncthreads();
    const size_t o = (size_t)(n0 + tr) * 512 + k0 + tc;
    #pragma unroll
    for (int j = 0; j < 4; j++) Whi[o + j] = f2bf(T[tc + j][tr]);
}

// π: permuted col j -> original col (head-fast split c2 = dd*8+h)
__device__ inline int qkv_perm(int j) {
    return (j >> 9) * 512 + ((j & 63) << 3) + ((j >> 6) & 7);
}

// ---------------------------------------------------------------------------
// 1-term bf16 MFMA GEMM, z = layer. A[4096][512] x Bt[N][512].
// EPI: 0 = qkv (B rows permuted, linear output, Q scaled),
//      1 = gelu -> bf16, 2 = plain bf16.
// BK=32; dbuf gll staging (stage kt+1 before compute kt, 1 barrier).
// ---------------------------------------------------------------------------
template<int BM, int EPI>
__global__ __launch_bounds__(256) void gemm_mfma(
    const u16* __restrict__ AB, const size_t aLS,
    const u16* __restrict__ BB, const size_t bLS,
    const float* __restrict__ bias0, const float* __restrict__ bias1, const int Ncols,
    u16* __restrict__ oh0, u16* __restrict__ oh1)
{
    constexpr int FM = BM / 32;
    __shared__ u16 Ah[2][BM * 32], Bh[2][128 * 32];
    const int z = blockIdx.z;
    const u16* A = AB + (size_t)z * aLS;
    const u16* B = BB + (size_t)z * bLS;
    const float* bias = z ? bias1 : bias0;
    u16* oh = z ? oh1 : oh0;

    const int t = threadIdx.x, l = t & 63, w = t >> 6;
    const int lr = l & 15, lg = l >> 4;
    const int wm = w >> 1, wn = w & 1;
    const int m0 = blockIdx.x * BM, n0 = blockIdx.y * 128;
    const int srow = l >> 2, sch = l & 3;    // staging lane coords (16 rows/KB)

    f32x4 acc[FM][4];
    #pragma unroll
    for (int i = 0; i < FM; i++)
        #pragma unroll
        for (int j = 0; j < 4; j++) acc[i][j] = f32x4{0.f, 0.f, 0.f, 0.f};

    auto stage = [&](int bufi, int k0) {
        #pragma unroll
        for (int i = 0; i < BM / 64; i++) {
            const int j = w * (BM / 64) + i;
            const int r = j * 16 + srow;
            const int ck = sch ^ ((r >> 1) & 3);
            gll16(&A[(size_t)(m0 + r) * 512 + k0 + ck * 8], &Ah[bufi][j * 512]);
        }
        #pragma unroll
        for (int i = 0; i < 2; i++) {
            const int j = w * 2 + i;
            const int r = j * 16 + srow;
            const int ck = sch ^ ((r >> 1) & 3);
            const int brow = (EPI == 0) ? qkv_perm(n0 + r) : (n0 + r);
            gll16(&B[(size_t)brow * 512 + k0 + ck * 8], &Bh[bufi][j * 512]);
        }
    };

    stage(0, 0);
    __syncthreads();
    int buf = 0;
    for (int kt = 0; kt < 16; kt++) {
        if (kt < 15) stage(buf ^ 1, (kt + 1) * 32);

        s16x8 ah[FM];
        #pragma unroll
        for (int fm = 0; fm < FM; fm++) {
            const int r = wm * (BM / 2) + fm * 16 + lr;
            ah[fm] = *(const s16x8*)&Ah[buf][r * 32 + ((lg ^ ((r >> 1) & 3)) << 3)];
        }
        #pragma unroll
        for (int fn = 0; fn < 4; fn++) {
            const int r = wn * 64 + fn * 16 + lr;
            s16x8 bh = *(const s16x8*)&Bh[buf][r * 32 + ((lg ^ ((r >> 1) & 3)) << 3)];
            #pragma unroll
            for (int fm = 0; fm < FM; fm++)
                acc[fm][fn] = __builtin_amdgcn_mfma_f32_16x16x32_bf16(ah[fm], bh, acc[fm][fn], 0, 0, 0);
        }
        __syncthreads();   // waves done with buf; stage(buf^1) drained
        buf ^= 1;
    }
    // epilogue
    #pragma unroll
    for (int fm = 0; fm < FM; fm++)
        #pragma unroll
        for (int fn = 0; fn < 4; fn++)
            #pragma unroll
            for (int rg = 0; rg < 4; rg++) {
                const int r = m0 + wm * (BM / 2) + fm * 16 + lg * 4 + rg;
                const int c = n0 + wn * 64 + fn * 16 + lr;
                if constexpr (EPI == 0) {
                    float v = acc[fm][fn][rg] + bias[qkv_perm(c)];
                    if (c < 512) v *= QSCALE;   // Q third (uniform per block)
                    oh[((size_t)z * 4096 + r) * Ncols + c] = f2bf(v);
                } else {
                    float gl = acc[fm][fn][rg] + bias[c];
                    if constexpr (EPI == 1)
                        gl = 0.5f * gl * (1.f + erff(gl * 0.70710678118654752f));
                    oh[(size_t)r * Ncols + c] = f2bf(gl);
                }
            }
}

// ---------------------------------------------------------------------------
// Flash attention, bf16 MFMA, z = layer (z==0 causal, z==1 anti-causal).
// R12 structure: att[2] pipeline — QK(t+1) -> PV(t) -> SM(t+1); swapped QK^T,
// lane-local softmax, in-register P, defer-max, setprio. (unchanged)
// ---------------------------------------------------------------------------
__global__ __launch_bounds__(256) void attn_mfma(const u16* __restrict__ QKV,
    float* __restrict__ AO0, float* __restrict__ AO1)
{
    __shared__ u16 Ks[2][64 * 64];
    __shared__ u16 Vs[2][64 * 64];
    const int t = threadIdx.x, l = t & 63, w = t >> 6;
    const int lr = l & 15, lg = l >> 4;
    const int z = blockIdx.z;
    const int causal = (z == 0);
    const int bh = blockIdx.x;
    const int b = bh >> 3, h = bh & 7;
    const int qt = causal ? (15 - (int)blockIdx.y) : (int)blockIdx.y;  // long jobs first
    const u16* base = QKV + ((size_t)z * 4096 + (size_t)b * NTOK) * 1536;
    float* AO = z ? AO1 : AO0;
    const int q0 = qt * 64 + w * 16;

    s16x8 aq[2];
    aq[0] = *(const s16x8*)&base[(size_t)(q0 + lr) * 1536 + h * 64 + lg * 8];
    aq[1] = *(const s16x8*)&base[(size_t)(q0 + lr) * 1536 + h * 64 + 32 + lg * 8];

    f32x4 o[4];
    float m_ = -INFINITY, l_ = 0.f;
    #pragma unroll
    for (int f = 0; f < 4; f++) o[f] = f32x4{0.f, 0.f, 0.f, 0.f};

    const int kt0 = causal ? 0 : qt, kt1 = causal ? qt : 15;

    auto stageK = [&](int kt) {
        #pragma unroll
        for (int i = 0; i < 2; i++) {
            const int j = w * 2 + i;
            const int r = j * 8 + (l >> 3);
            const int ck = (l & 7) ^ (r & 7);
            gll16(&base[(size_t)(kt * 64 + r) * 1536 + 512 + h * 64 + ck * 8],
                  &Ks[kt & 1][j * 512]);
        }
    };
    const int jv = t & 63;
    s16x8 va, vb;
    auto loadV = [&](int kt) {
        const u16* vr = &base[(size_t)(kt * 64 + jv) * 1536 + 1024 + h * 64 + w * 16];
        va = *(const s16x8*)&vr[0];
        vb = *(const s16x8*)&vr[8];
    };
    auto writeV = [&](int kt) {
        #pragma unroll
        for (int i = 0; i < 8; i++) {
            const int d = w * 16 + i;
            Vs[kt & 1][d * 64 + (((jv >> 3) ^ (d & 7)) << 3) + (jv & 7)] = (u16)va[i];
        }
        #pragma unroll
        for (int i = 0; i < 8; i++) {
            const int d = w * 16 + 8 + i;
            Vs[kt & 1][d * 64 + (((jv >> 3) ^ (d & 7)) << 3) + (jv & 7)] = (u16)vb[i];
        }
    };

    s16x8 pap[2];
    float psc[4] = {1.f, 1.f, 1.f, 1.f};
    int pneed = 1;

    auto QK = [&](int kt, f32x4* s) {
        #pragma unroll
        for (int f = 0; f < 4; f++) s[f] = f32x4{0.f, 0.f, 0.f, 0.f};
        #pragma unroll
        for (int kk = 0; kk < 2; kk++)
            #pragma unroll
            for (int f = 0; f < 4; f++) {
                const int row = f * 16 + lr;
                const int ch = kk * 4 + lg;
                s16x8 bk = *(const s16x8*)&Ks[kt & 1][row * 64 + ((ch ^ (row & 7)) << 3)];
                s[f] = __builtin_amdgcn_mfma_f32_16x16x32_bf16(bk, aq[kk], s[f], 0, 0, 0);
            }
        if (kt == qt) {
            const int q = q0 + lr;
            #pragma unroll
            for (int f = 0; f < 4; f++)
                #pragma unroll
                for (int r = 0; r < 4; r++) {
                    const int key = kt * 64 + f * 16 + lg * 4 + r;
                    if (causal ? (key > q) : (key < q)) s[f][r] = -INFINITY;
                }
        }
    };

    auto SM = [&](f32x4* s) {
        float rm = s[0][0];
        #pragma unroll
        for (int f = 0; f < 4; f++)
            #pragma unroll
            for (int r = 0; r < 4; r++) rm = fmaxf(rm, s[f][r]);
        rm = fmaxf(rm, __shfl_xor(rm, 16));
        rm = fmaxf(rm, __shfl_xor(rm, 32));
        pneed = !__all(rm <= m_ + 8.f);          // defer-max (T13)
        const float mn = pneed ? fmaxf(m_, rm) : m_;
        const float sc = __expf(m_ - mn);        // ==1 when deferred
        float ps = 0.f;
        #pragma unroll
        for (int f = 0; f < 4; f++)
            #pragma unroll
            for (int r = 0; r < 4; r++) {
                float p = __expf(s[f][r] - mn);
                s[f][r] = p;
                ps += p;
            }
        ps += __shfl_xor(ps, 16);
        ps += __shfl_xor(ps, 32);
        l_ = l_ * sc + ps;
        m_ = mn;
        u32 P01[4], P23[4];
        #pragma unroll
        for (int f = 0; f < 4; f++) {
            P01[f] = cvtpk(s[f][0], s[f][1]);
            P23[f] = cvtpk(s[f][2], s[f][3]);
        }
        const int srcA = lr + ((lg & 1) << 5);
        const int srcB = srcA + 16;
        #pragma unroll
        for (int kk = 0; kk < 2; kk++) {
            const u32 a01_0 = (u32)__shfl((int)P01[2 * kk], srcA);
            const u32 a01_1 = (u32)__shfl((int)P01[2 * kk + 1], srcA);
            const u32 a23_0 = (u32)__shfl((int)P23[2 * kk], srcA);
            const u32 a23_1 = (u32)__shfl((int)P23[2 * kk + 1], srcA);
            const u32 b01_0 = (u32)__shfl((int)P01[2 * kk], srcB);
            const u32 b01_1 = (u32)__shfl((int)P01[2 * kk + 1], srcB);
            const u32 b23_0 = (u32)__shfl((int)P23[2 * kk], srcB);
            const u32 b23_1 = (u32)__shfl((int)P23[2 * kk + 1], srcB);
            i32x4 av;
            av[0] = (int)((lg & 2) ? a01_1 : a01_0);
            av[1] = (int)((lg & 2) ? a23_1 : a23_0);
            av[2] = (int)((lg & 2) ? b01_1 : b01_0);
            av[3] = (int)((lg & 2) ? b23_1 : b23_0);
            pap[kk] = __builtin_bit_cast(s16x8, av);
        }
        if (pneed) {
            #pragma unroll
            for (int r = 0; r < 4; r++) psc[r] = __shfl(sc, lg * 4 + r);
        }
    };

    auto PV = [&](int kt) {
        if (pneed) {
            #pragma unroll
            for (int r = 0; r < 4; r++)
                #pragma unroll
                for (int f = 0; f < 4; f++) o[f][r] *= psc[r];
        }
        #pragma unroll
        for (int kk = 0; kk < 2; kk++)
            #pragma unroll
            for (int f = 0; f < 4; f++) {
                const int row = f * 16 + lr;
                const int ch = kk * 4 + lg;
                s16x8 bv = *(const s16x8*)&Vs[kt & 1][row * 64 + ((ch ^ (row & 7)) << 3)];
                o[f] = __builtin_amdgcn_mfma_f32_16x16x32_bf16(pap[kk], bv, o[f], 0, 0, 0);
            }
    };

    // ---- prologue ----
    stageK(kt0);
    if (kt0 < kt1) stageK(kt0 + 1);
    loadV(kt0);
    writeV(kt0);
    __syncthreads();
    {
        f32x4 s0[4];
        QK(kt0, s0);
        SM(s0);
    }
    __syncthreads();

    // ---- main loop: QK(t+1) -> PV(t) -> SM(t+1) ----
    for (int kt = kt0; kt <= kt1; kt++) {
        if (kt + 2 <= kt1) stageK(kt + 2);
        if (kt + 1 <= kt1) loadV(kt + 1);
        f32x4 sn[4];
        __builtin_amdgcn_s_setprio(1);
        if (kt + 1 <= kt1) QK(kt + 1, sn);
        PV(kt);
        __builtin_amdgcn_s_setprio(0);
        if (kt + 1 <= kt1) {
            SM(sn);
            writeV(kt + 1);
        }
        __syncthreads();
    }

    // ---- epilogue ----
    const float linv = 1.f / l_;
    #pragma unroll
    for (int r = 0; r < 4; r++) {
        const float lv = __shfl(linv, lg * 4 + r);
        #pragma unroll
        for (int f = 0; f < 4; f++)
            AO[(size_t)(b * NTOK + q0 + lg * 4 + r) * PL + h * 64 + f * 16 + lr] = o[f][r] * lv;
    }
}

// ---------------------------------------------------------------------------
// add+LN A: x(f32)+attn(f32) -> LN -> single bf16 x1. z = layer.
// ---------------------------------------------------------------------------
__global__ __launch_bounds__(256) void add_ln_a(const float* __restrict__ X,
    const float* __restrict__ A0, const float* __restrict__ A1,
    const float* __restrict__ g0, const float* __restrict__ g1,
    const float* __restrict__ be0, const float* __restrict__ be1,
    u16* __restrict__ OB, const size_t oLS)
{
    const int z = blockIdx.z;
    const float* A = z ? A1 : A0;
    const float* g = z ? g1 : g0;
    const float* be = z ? be1 : be0;
    u16* O = OB + (size_t)z * oLS;
    const int row = blockIdx.x * 4 + (threadIdx.x >> 6);
    const int lane = threadIdx.x & 63;
    const float* xr = X + (size_t)row * PL;
    const float* ar = A + (size_t)row * PL;
    float v[8];
    float sum = 0.f;
    #pragma unroll
    for (int u = 0; u < 8; u++) { v[u] = xr[lane + u * 64] + ar[lane + u * 64]; sum += v[u]; }
    #pragma unroll
    for (int o = 32; o > 0; o >>= 1) sum += __shfl_xor(sum, o);
    const float mu = sum * (1.f / 512.f);
    float s2 = 0.f;
    #pragma unroll
    for (int u = 0; u < 8; u++) { float d = v[u] - mu; s2 = fmaf(d, d, s2); }
    #pragma unroll
    for (int o = 32; o > 0; o >>= 1) s2 += __shfl_xor(s2, o);
    const float rstd = rsqrtf(s2 * (1.f / 512.f) + 1e-5f);
    #pragma unroll
    for (int u = 0; u < 8; u++) {
        const int c = lane + u * 64;
        O[(size_t)row * PL + c] = f2bf((v[u] - mu) * rstd * g[c] + be[c]);
    }
}

// ---------------------------------------------------------------------------
// add+LN B: x1(bf16) + ffo(bf16) -> LN -> sigmoid -> bf16 td. z = layer.
// ---------------------------------------------------------------------------
__global__ __launch_bounds__(256) void add_ln_b(
    const u16* __restrict__ X1B, const size_t xLS,
    const u16* __restrict__ FB, const size_t fLS,
    const float* __restrict__ g0, const float* __restrict__ g1,
    const float* __restrict__ be0, const float* __restrict__ be1,
    u16* __restrict__ TDB, const size_t tLS)
{
    const int z = blockIdx.z;
    const u16* X1 = X1B + (size_t)z * xLS;
    const u16* F = FB + (size_t)z * fLS;
    const float* g = z ? g1 : g0;
    const float* be = z ? be1 : be0;
    u16* TD = TDB + (size_t)z * tLS;
    const int row = blockIdx.x * 4 + (threadIdx.x >> 6);
    const int lane = threadIdx.x & 63;
    const size_t ro = (size_t)row * PL;
    float v[8];
    float sum = 0.f;
    #pragma unroll
    for (int u = 0; u < 8; u++) {
        const int c = lane + u * 64;
        v[u] = bf2f(X1[ro + c]) + bf2f(F[ro + c]);
        sum += v[u];
    }
    #pragma unroll
    for (int o = 32; o > 0; o >>= 1) sum += __shfl_xor(sum, o);
    const float mu = sum * (1.f / 512.f);
    float s2 = 0.f;
    #pragma unroll
    for (int u = 0; u < 8; u++) { float d = v[u] - mu; s2 = fmaf(d, d, s2); }
    #pragma unroll
    for (int o = 32; o > 0; o >>= 1) s2 += __shfl_xor(s2, o);
    const float rstd = rsqrtf(s2 * (1.f / 512.f) + 1e-5f);
    #pragma unroll
    for (int u = 0; u < 8; u++) {
        const int c = lane + u * 64;
        float y = (v[u] - mu) * rstd * g[c] + be[c];
        TD[ro + c] = f2bf(1.f / (1.f + expf(-y)));
    }
}

// ---------------------------------------------------------------------------
// sim: per batch, C[i][j] = dot(td1[i,:], td2[j,:]) / 512  (plain bf16 MFMA)
// 64x128 tiles -> 512 blocks. gll-staged, BK=64, dbuf.
// ---------------------------------------------------------------------------
__global__ __launch_bounds__(256) void sim_mfma(const u16* __restrict__ TD1,
    const u16* __restrict__ TD2, float* __restrict__ Out)
{
    __shared__ u16 Ah[2][64 * 64], Bh[2][128 * 64];
    const int t = threadIdx.x, l = t & 63, w = t >> 6;
    const int lr = l & 15, lg = l >> 4;
    const int wm = w >> 1, wn = w & 1;
    const int bz = blockIdx.z;
    const u16* A = TD1 + (size_t)bz * NTOK * PL;
    const u16* B = TD2 + (size_t)bz * NTOK * PL;
    const int m0 = blockIdx.x * 64, n0 = blockIdx.y * 128;

    f32x4 acc[2][4];
    #pragma unroll
    for (int i = 0; i < 2; i++)
        #pragma unroll
        for (int j = 0; j < 4; j++) acc[i][j] = f32x4{0.f, 0.f, 0.f, 0.f};

    auto stage = [&](int bufi, int k0) {
        #pragma unroll
        for (int i = 0; i < 2; i++) {
            const int j = w * 2 + i;
            const int r = j * 8 + (l >> 3);
            const int ck = (l & 7) ^ (r & 7);
            gll16(&A[(size_t)(m0 + r) * 512 + k0 + ck * 8], &Ah[bufi][j * 512]);
        }
        #pragma unroll
        for (int i = 0; i < 4; i++) {
            const int j = w * 4 + i;
            const int r = j * 8 + (l >> 3);
            const int ck = (l & 7) ^ (r & 7);
            gll16(&B[(size_t)(n0 + r) * 512 + k0 + ck * 8], &Bh[bufi][j * 512]);
        }
    };

    stage(0, 0);
    __syncthreads();
    int buf = 0;
    for (int kt = 0; kt < 8; kt++) {
        if (kt < 7) stage(buf ^ 1, (kt + 1) * 64);
        #pragma unroll
        for (int kk = 0; kk < 2; kk++) {
            const int ch = kk * 4 + lg;
            s16x8 af[2], bf[4];
            #pragma unroll
            for (int fm = 0; fm < 2; fm++) {
                const int r = wm * 32 + fm * 16 + lr;
                af[fm] = *(const s16x8*)&Ah[buf][r * 64 + ((ch ^ (r & 7)) << 3)];
            }
            #pragma unroll
            for (int fn = 0; fn < 4; fn++) {
                const int r = wn * 64 + fn * 16 + lr;
                bf[fn] = *(const s16x8*)&Bh[buf][r * 64 + ((ch ^ (r & 7)) << 3)];
            }
            #pragma unroll
            for (int fm = 0; fm < 2; fm++)
                #pragma unroll
                for (int fn = 0; fn < 4; fn++)
                    acc[fm][fn] = __builtin_amdgcn_mfma_f32_16x16x32_bf16(af[fm], bf[fn], acc[fm][fn], 0, 0, 0);
        }
        __syncthreads();
        buf ^= 1;
    }
    #pragma unroll
    for (int fm = 0; fm < 2; fm++)
        #pragma unroll
        for (int fn = 0; fn < 4; fn++)
            #pragma unroll
            for (int rg = 0; rg < 4; rg++) {
                const int r = m0 + wm * 32 + fm * 16 + lg * 4 + rg;
                const int c = n0 + wn * 64 + fn * 16 + lr;
                Out[((size_t)(bz * NTOK + r)) * NTOK + c] = acc[fm][fn][rg] * (1.f / 512.f);
            }
}

// ---------------------------------------------------------------------------
extern "C" void kernel_launch(void* const* d_in, const int* in_sizes, int n_in,
                              void* d_out, int out_size, void* d_ws, size_t ws_size,
                              hipStream_t stream)
{
    const float* x = (const float*)d_in[0];
    const float* wqkv[2] = {(const float*)d_in[1],  (const float*)d_in[11]};
    const float* bqkv[2] = {(const float*)d_in[2],  (const float*)d_in[12]};
    const float* ga[2]   = {(const float*)d_in[3],  (const float*)d_in[13]};
    const float* bea[2]  = {(const float*)d_in[4],  (const float*)d_in[14]};
    const float* w1[2]   = {(const float*)d_in[5],  (const float*)d_in[15]};
    const float* b1[2]   = {(const float*)d_in[6],  (const float*)d_in[16]};
    const float* w2[2]   = {(const float*)d_in[7],  (const float*)d_in[17]};
    const float* b2[2]   = {(const float*)d_in[8],  (const float*)d_in[18]};
    const float* gb[2]   = {(const float*)d_in[9],  (const float*)d_in[19]};
    const float* beb[2]  = {(const float*)d_in[10], (const float*)d_in[20]};

    // -------- workspace map (KB offsets; lifetimes verified stage-by-stage) --
    char* wsb = (char*)d_ws;
    char* ob  = (char*)d_out;
    #define WSK(kb) ((char*)wsb + ((size_t)(kb) << 10))
    #define OBK(kb) ((char*)ob  + ((size_t)(kb) << 10))
    // ws [0,4M):  xhi (S0-S2);  ws [0,8M): x1 z0/z1 (S4-S7)
    u16* xhi = (u16*)WSK(0);
    u16* x1  = (u16*)WSK(0);          // + z*2097152 elems
    // ws [8,11M): wqh (S1-S2) -> td (S7-): td1 [8,12M), td2 [12,16M)
    u16* wqh = (u16*)WSK(8192);       // + z*786432 elems
    u16* td1 = (u16*)WSK(8192);
    u16* td2 = (u16*)WSK(12288);
    // ws [11,13M): w1h [11,12M), w2h [12,13M) (S1-S6; dead before td writes)
    u16* w1h = (u16*)WSK(11264);      // + z*262144 elems
    u16* w2h = (u16*)WSK(12288);      // + z*262144 elems
    // ws [13,37M): qkvB (S2-S3)
    u16* qkvB = (u16*)WSK(13312);     // [z][4096][1536]
    // ws [24,32M): ffo single bf16 (S6-S7; qkvB dead)
    u16* ffo = (u16*)WSK(24576);      // + z*2097152 elems
    // d_out: AO0/AO1 f32 (S3-S4); h bf16 (S5-S6); final out (S8)
    float* AO0 = (float*)OBK(0);
    float* AO1 = (float*)OBK(8192);
    u16* hB = (u16*)OBK(0);           // + z*2097152 elems
    float* out = (float*)d_out;

    // S0+S1: merged prep (x convert + 3 weight transposes)
    prep<<<4608, 256, 0, stream>>>(x, xhi,
        wqkv[0], wqkv[1], wqh, w1[0], w1[1], w1h, w2[0], w2[1], w2h);
    // S2: qkv gemm — 1-term, permuted-B, linear output into qkvB
    gemm_mfma<128, 0><<<dim3(32, 12, 2), 256, 0, stream>>>(
        xhi, 0, wqh, 786432, bqkv[0], bqkv[1], 1536,
        qkvB, qkvB);
    // S3: attention (z=0 causal, z=1 anti-causal)
    attn_mfma<<<dim3(32, 16, 2), 256, 0, stream>>>(qkvB, AO0, AO1);
    // S4: add + LN -> x1 single bf16
    add_ln_a<<<dim3(1024, 1, 2), 256, 0, stream>>>(x, AO0, AO1,
        ga[0], ga[1], bea[0], bea[1], x1, 2097152);
    // S5: ff1 (gelu) -> h bf16 (d_out), 1-term
    gemm_mfma<64, 1><<<dim3(64, 4, 2), 256, 0, stream>>>(
        x1, 2097152, w1h, 262144, b1[0], b1[1], 512,
        hB, hB + 2097152);
    // S6: ff2 -> ffo bf16 (ws), 1-term
    gemm_mfma<64, 2><<<dim3(64, 4, 2), 256, 0, stream>>>(
        hB, 2097152, w2h, 262144, b2[0], b2[1], 512,
        ffo, ffo + 2097152);
    // S7: add + LN + sigmoid -> td
    add_ln_b<<<dim3(1024, 1, 2), 256, 0, stream>>>(
        x1, 2097152, ffo, 2097152,
        gb[0], gb[1], beb[0], beb[1], td1, 2097152);
    // S8: sim (64x128 tiles, 512 blocks)
    sim_mfma<<<dim3(16, 8, 4), 256, 0, stream>>>(td1, td2, out);
}